// Round 1
// baseline (436.316 us; speedup 1.0000x reference)
//
#include <hip/hip_runtime.h>
#include <hip/hip_bf16.h>

typedef __bf16 bf16x8 __attribute__((ext_vector_type(8)));
typedef __bf16 bf16x4 __attribute__((ext_vector_type(4)));
typedef float  f32x4  __attribute__((ext_vector_type(4)));
typedef unsigned int u32;
typedef u32 u32x2 __attribute__((ext_vector_type(2)));
typedef u32 u32x4 __attribute__((ext_vector_type(4)));
typedef u32x2 __attribute__((may_alias)) u32x2a;
typedef u32x4 __attribute__((may_alias)) u32x4a;

#define S_  2048
#define E_  1024
#define NH_ 64

__device__ __forceinline__ f32x4 mfma16(bf16x8 a, bf16x8 b, f32x4 c) {
    return __builtin_amdgcn_mfma_f32_16x16x32_bf16(a, b, c, 0, 0, 0);
}

__device__ __forceinline__ u32x2 pack4(float a, float b, float c, float d) {
    bf16x4 h;
    h[0] = (__bf16)a; h[1] = (__bf16)b; h[2] = (__bf16)c; h[3] = (__bf16)d;
    return __builtin_bit_cast(u32x2, h);
}

// ---------------------------------------------------------------- Wo -> bf16
__global__ __launch_bounds__(256) void k_cast_wo(const float* __restrict__ Wo,
                                                 __bf16* __restrict__ Wob) {
    int i = (blockIdx.x * 256 + threadIdx.x) * 8;
    float4 a = *(const float4*)(Wo + i);
    float4 b = *(const float4*)(Wo + i + 4);
    bf16x8 f;
    f[0] = (__bf16)a.x; f[1] = (__bf16)a.y; f[2] = (__bf16)a.z; f[3] = (__bf16)a.w;
    f[4] = (__bf16)b.x; f[5] = (__bf16)b.y; f[6] = (__bf16)b.z; f[7] = (__bf16)b.w;
    *(bf16x8*)(Wob + i) = f;
}

// ------------------------------------------------- QKV per-head projections
// z=0: values -> Vt[nh][d][s] (transposed), z=1: keys -> Kws[nh][s][d],
// z=2: query -> Qws[nh][s][d] with log2(e)/32 folded into Wq.
__global__ __launch_bounds__(256) void k_proj(const float* __restrict__ vin,
                                              const float* __restrict__ kin,
                                              const float* __restrict__ qin,
                                              const float* __restrict__ Wv,
                                              const float* __restrict__ Wk,
                                              const float* __restrict__ Wq,
                                              __bf16* __restrict__ Qws,
                                              __bf16* __restrict__ Kws,
                                              __bf16* __restrict__ Vt) {
    const int z = blockIdx.z;
    const float* in = (z == 0) ? vin : ((z == 1) ? kin : qin);
    const float* W  = (z == 0) ? Wv  : ((z == 1) ? Wk  : Wq);
    const float scale = (z == 2) ? 0.04508422f : 1.0f;  // log2(e)/32
    const int bid  = blockIdx.x;
    const int nh   = bid >> 5;           // 0..63
    const int sblk = (bid & 31) << 6;    // 64 s-rows per block
    const int n = nh >> 4, h = nh & 15;
    const int lane = threadIdx.x & 63, wid = threadIdx.x >> 6;
    const int l16 = lane & 15, g = lane >> 4;

    // B-fragments from W: B[d][e] = W[e][d]; lane holds row e=l16(+16nt), d-slice
    bf16x8 Bf[4][2];
#pragma unroll
    for (int nt = 0; nt < 4; ++nt)
#pragma unroll
        for (int ks = 0; ks < 2; ++ks) {
            const float* wp = W + (nt * 16 + l16) * 64 + ks * 32 + g * 8;
            float4 a = *(const float4*)wp;
            float4 b = *(const float4*)(wp + 4);
            bf16x8 f;
            f[0] = (__bf16)(a.x * scale); f[1] = (__bf16)(a.y * scale);
            f[2] = (__bf16)(a.z * scale); f[3] = (__bf16)(a.w * scale);
            f[4] = (__bf16)(b.x * scale); f[5] = (__bf16)(b.y * scale);
            f[6] = (__bf16)(b.z * scale); f[7] = (__bf16)(b.w * scale);
            Bf[nt][ks] = f;
        }

    // A-fragments: input rows (n, s, h) — lane holds row s=l16, d-slice
    const int s = sblk + wid * 16 + l16;
    const float* ip = in + ((size_t)n * S_ + s) * E_ + h * 64 + g * 8;
    bf16x8 Af[2];
#pragma unroll
    for (int ks = 0; ks < 2; ++ks) {
        float4 a = *(const float4*)(ip + ks * 32);
        float4 b = *(const float4*)(ip + ks * 32 + 4);
        bf16x8 f;
        f[0] = (__bf16)a.x; f[1] = (__bf16)a.y; f[2] = (__bf16)a.z; f[3] = (__bf16)a.w;
        f[4] = (__bf16)b.x; f[5] = (__bf16)b.y; f[6] = (__bf16)b.z; f[7] = (__bf16)b.w;
        Af[ks] = f;
    }

    f32x4 acc[4];
#pragma unroll
    for (int nt = 0; nt < 4; ++nt) { acc[nt][0] = 0.f; acc[nt][1] = 0.f; acc[nt][2] = 0.f; acc[nt][3] = 0.f; }
#pragma unroll
    for (int nt = 0; nt < 4; ++nt) {
        acc[nt] = mfma16(Af[0], Bf[nt][0], acc[nt]);
        acc[nt] = mfma16(Af[1], Bf[nt][1], acc[nt]);
    }

    // D[s][e]: col e = nt*16+l16, row s = wid*16 + g*4 + r
    if (z == 0) {
#pragma unroll
        for (int nt = 0; nt < 4; ++nt)
#pragma unroll
            for (int r = 0; r < 4; ++r) {
                int e = nt * 16 + l16;
                int srow = sblk + wid * 16 + g * 4 + r;
                Vt[((size_t)nh * 64 + e) * S_ + srow] = (__bf16)acc[nt][r];
            }
    } else {
        __bf16* O = (z == 1) ? Kws : Qws;
#pragma unroll
        for (int nt = 0; nt < 4; ++nt)
#pragma unroll
            for (int r = 0; r < 4; ++r) {
                int srow = sblk + wid * 16 + g * 4 + r;
                O[((size_t)nh * S_ + srow) * 64 + nt * 16 + l16] = (__bf16)acc[nt][r];
            }
    }
}

// ----------------------------------------------------------- flash attention
// Per block: one (n,h), 128 q-rows. Per wave: 32 q (2 sub-tiles of 16).
// S^T = mfma(K_frag, Q_frag)  -> D[k][q]  (q = lane&15, lane-local k slots)
// p = exp2(s)  (scale folded into Wq);  l-sum is per-lane, reduced once at end
// P^T -> LDS (XOR-swizzled) -> B-frags;  O^T = mfma(Vt_frag, P_frag)
__global__ __launch_bounds__(256) void k_attn(const __bf16* __restrict__ Qws,
                                              const __bf16* __restrict__ Kws,
                                              const __bf16* __restrict__ Vt,
                                              const int* __restrict__ maskp,
                                              __bf16* __restrict__ Xws) {
    __shared__ u32 Plds[4][512];  // 2KB per wave: P^T tile [16 q][64 k] bf16, swizzled
    const int tid = threadIdx.x, lane = tid & 63, wid = tid >> 6;
    const int q16 = lane & 15, g = lane >> 4;
    const int bid = blockIdx.x;
    const int nh = bid >> 4;
    const int qblk = (bid & 15) << 7;  // 128 q per block
    const int n = nh >> 4, h = nh & 15;

    // block-uniform mask scan (mask is all-ones in practice -> fast path)
    int az = 0;
    for (int i = tid; i < S_; i += 256) az |= (maskp[(size_t)n * S_ + i] == 0);
    const int anyzero = __syncthreads_or(az);

    const __bf16* Qb = Qws + (size_t)nh * S_ * 64;
    const __bf16* Kb = Kws + (size_t)nh * S_ * 64;
    const __bf16* Vb = Vt  + (size_t)nh * 64 * S_;

    const int q0 = qblk + wid * 32;
    bf16x8 Qf[2][2];
#pragma unroll
    for (int qt = 0; qt < 2; ++qt)
#pragma unroll
        for (int ks = 0; ks < 2; ++ks)
            Qf[qt][ks] = *(const bf16x8*)(Qb + (size_t)(q0 + qt * 16 + q16) * 64 + ks * 32 + g * 8);

    f32x4 acc[2][4];
#pragma unroll
    for (int qt = 0; qt < 2; ++qt)
#pragma unroll
        for (int md = 0; md < 4; ++md) { acc[qt][md][0] = 0.f; acc[qt][md][1] = 0.f; acc[qt][md][2] = 0.f; acc[qt][md][3] = 0.f; }
    float lsum[2] = {0.f, 0.f};

    char* pb = (char*)&Plds[wid][0];
    const int swz = (q16 & 7) << 4;  // XOR on byte bits 4-6: kills 16-way row conflicts

    for (int kb = 0; kb < 32; ++kb) {
        const int k0 = kb * 64;
        bf16x8 Kf[4][2], Vf[4][2];
#pragma unroll
        for (int m = 0; m < 4; ++m)
#pragma unroll
            for (int ks = 0; ks < 2; ++ks) {
                Kf[m][ks] = *(const bf16x8*)(Kb + (size_t)(k0 + m * 16 + q16) * 64 + ks * 32 + g * 8);
                Vf[m][ks] = *(const bf16x8*)(Vb + (size_t)(m * 16 + q16) * S_ + k0 + ks * 32 + g * 8);
            }
#pragma unroll
        for (int qt = 0; qt < 2; ++qt) {
            f32x4 sv[4];
#pragma unroll
            for (int m = 0; m < 4; ++m) {
                f32x4 z; z[0] = 0.f; z[1] = 0.f; z[2] = 0.f; z[3] = 0.f;
                sv[m] = mfma16(Kf[m][0], Qf[qt][0], z);
                sv[m] = mfma16(Kf[m][1], Qf[qt][1], sv[m]);
            }
            if (anyzero) {  // slow path only if mask has zeros
#pragma unroll
                for (int m = 0; m < 4; ++m)
#pragma unroll
                    for (int r = 0; r < 4; ++r) {
                        int kk = k0 + m * 16 + g * 4 + r;
                        if (maskp[(size_t)n * S_ + kk] == 0) sv[m][r] = -1e30f;
                    }
            }
#pragma unroll
            for (int m = 0; m < 4; ++m) {
                float p0 = __builtin_amdgcn_exp2f(sv[m][0]);
                float p1 = __builtin_amdgcn_exp2f(sv[m][1]);
                float p2 = __builtin_amdgcn_exp2f(sv[m][2]);
                float p3 = __builtin_amdgcn_exp2f(sv[m][3]);
                lsum[qt] += (p0 + p1) + (p2 + p3);
                // lane holds P^T[k=16m+4g+r][q=q16]; write 4 bf16 (8B) swizzled
                u32x2 w = pack4(p0, p1, p2, p3);
                *(u32x2a*)(pb + (q16 << 7) + (((m << 5) + (g << 3)) ^ swz)) = w;
            }
            // read back as B-fragments: lane = col q16, k-slice ks2*32 + g*8
            bf16x8 Pf[2];
#pragma unroll
            for (int ks2 = 0; ks2 < 2; ++ks2) {
                u32x4a t = *(const u32x4a*)(pb + (q16 << 7) + (((ks2 << 6) + (g << 4)) ^ swz));
                Pf[ks2] = __builtin_bit_cast(bf16x8, t);
            }
#pragma unroll
            for (int md = 0; md < 4; ++md) {
                acc[qt][md] = mfma16(Vf[md][0], Pf[0], acc[qt][md]);
                acc[qt][md] = mfma16(Vf[md][1], Pf[1], acc[qt][md]);
            }
        }
    }

#pragma unroll
    for (int qt = 0; qt < 2; ++qt) {
        float lt = lsum[qt];
        lt += __shfl_xor(lt, 16);
        lt += __shfl_xor(lt, 32);
        const float inv = 1.0f / lt;
        const int qg = q0 + qt * 16 + q16;
#pragma unroll
        for (int md = 0; md < 4; ++md)
#pragma unroll
            for (int r = 0; r < 4; ++r) {
                int d = md * 16 + g * 4 + r;  // O^T: row=d, col=q
                Xws[((size_t)(n * S_ + qg)) * E_ + h * 64 + d] = (__bf16)(acc[qt][md][r] * inv);
            }
    }
}

// ------------------------------------------------------- output GEMM + bias
// Y[m][o] = sum_e X[m][e] * Wo[o][e] + bo[o];  M=8192, N=1024, K=1024
__global__ __launch_bounds__(256) void k_out(const __bf16* __restrict__ Xws,
                                             const __bf16* __restrict__ Wob,
                                             const float* __restrict__ bo,
                                             float* __restrict__ out) {
    const int bid = blockIdx.x;
    const int mblk = bid & 127, nblk = bid >> 7;
    const int lane = threadIdx.x & 63, wid = threadIdx.x >> 6;
    const int l16 = lane & 15, g = lane >> 4;
    const int m0 = mblk * 64 + wid * 16;
    const int o0 = nblk * 128;

    f32x4 acc[8];
#pragma unroll
    for (int nt = 0; nt < 8; ++nt) { acc[nt][0] = 0.f; acc[nt][1] = 0.f; acc[nt][2] = 0.f; acc[nt][3] = 0.f; }

    const __bf16* Xp = Xws + ((size_t)m0 + l16) * E_ + g * 8;
    const __bf16* Wp = Wob + ((size_t)o0 + l16) * E_ + g * 8;

#pragma unroll 2
    for (int ks = 0; ks < 32; ++ks) {
        bf16x8 Aa = *(const bf16x8*)(Xp + ks * 32);
#pragma unroll
        for (int nt = 0; nt < 8; ++nt) {
            bf16x8 Bb = *(const bf16x8*)(Wp + (size_t)nt * 16 * E_ + ks * 32);
            acc[nt] = mfma16(Aa, Bb, acc[nt]);
        }
    }
#pragma unroll
    for (int nt = 0; nt < 8; ++nt) {
        float bias = bo[o0 + nt * 16 + l16];
#pragma unroll
        for (int r = 0; r < 4; ++r)
            out[((size_t)m0 + g * 4 + r) * E_ + o0 + nt * 16 + l16] = acc[nt][r] + bias;
    }
}

extern "C" void kernel_launch(void* const* d_in, const int* in_sizes, int n_in,
                              void* d_out, int out_size, void* d_ws, size_t ws_size,
                              hipStream_t stream) {
    const float* vin  = (const float*)d_in[0];
    const float* kin  = (const float*)d_in[1];
    const float* qin  = (const float*)d_in[2];
    const int*   mask = (const int*)d_in[3];
    const float* Wv   = (const float*)d_in[4];
    const float* Wk   = (const float*)d_in[5];
    const float* Wq   = (const float*)d_in[6];
    const float* Wo   = (const float*)d_in[7];
    const float* bo   = (const float*)d_in[8];

    __bf16* Qws = (__bf16*)d_ws;                       // [64][2048][64]
    __bf16* Kws = Qws + (size_t)NH_ * S_ * 64;         // [64][2048][64]
    __bf16* Vt  = Kws + (size_t)NH_ * S_ * 64;         // [64][64][2048]
    __bf16* Xws = Vt  + (size_t)NH_ * S_ * 64;         // [4][2048][1024]
    __bf16* Wob = Xws + (size_t)4 * S_ * E_;           // [1024][1024]
    float* out = (float*)d_out;

    hipLaunchKernelGGL(k_cast_wo, dim3(512), dim3(256), 0, stream, Wo, Wob);
    hipLaunchKernelGGL(k_proj, dim3(2048, 1, 3), dim3(256), 0, stream,
                       vin, kin, qin, Wv, Wk, Wq, Qws, Kws, Vt);
    hipLaunchKernelGGL(k_attn, dim3(1024), dim3(256), 0, stream, Qws, Kws, Vt, mask, Xws);
    hipLaunchKernelGGL(k_out, dim3(1024), dim3(256), 0, stream, Xws, Wob, bo, out);
}

// Round 2
// 407.417 us; speedup vs baseline: 1.0709x; 1.0709x over previous
//
#include <hip/hip_runtime.h>
#include <hip/hip_bf16.h>

typedef __bf16 bf16x8 __attribute__((ext_vector_type(8)));
typedef __bf16 bf16x4 __attribute__((ext_vector_type(4)));
typedef __bf16 bf16x2 __attribute__((ext_vector_type(2)));
typedef float  f32x4  __attribute__((ext_vector_type(4)));
typedef float  f32x16 __attribute__((ext_vector_type(16)));
typedef unsigned int u32;
typedef u32 u32x4 __attribute__((ext_vector_type(4)));

#define S_  2048
#define E_  1024
#define NH_ 64

__device__ __forceinline__ f32x4 mfma16(bf16x8 a, bf16x8 b, f32x4 c) {
    return __builtin_amdgcn_mfma_f32_16x16x32_bf16(a, b, c, 0, 0, 0);
}
__device__ __forceinline__ f32x16 mfma32(bf16x8 a, bf16x8 b, f32x16 c) {
    return __builtin_amdgcn_mfma_f32_32x32x16_bf16(a, b, c, 0, 0, 0);
}
__device__ __forceinline__ u32 pack2(float a, float b) {
    bf16x2 t; t[0] = (__bf16)a; t[1] = (__bf16)b;   // compiler fuses to v_cvt_pk_bf16_f32
    return __builtin_bit_cast(u32, t);
}
// a' = {a_lo, b_lo}; b' = {a_hi, b_hi}  (swap upper 32 lanes of a with lower 32 of b)
__device__ __forceinline__ void swap32(u32& a, u32& b) {
    asm("v_permlane32_swap_b32 %0, %1" : "+v"(a), "+v"(b));
}

// ---------------------------------------------------------------- Wo -> bf16
__global__ __launch_bounds__(256) void k_cast_wo(const float* __restrict__ Wo,
                                                 __bf16* __restrict__ Wob) {
    int i = (blockIdx.x * 256 + threadIdx.x) * 8;
    float4 a = *(const float4*)(Wo + i);
    float4 b = *(const float4*)(Wo + i + 4);
    bf16x8 f;
    f[0] = (__bf16)a.x; f[1] = (__bf16)a.y; f[2] = (__bf16)a.z; f[3] = (__bf16)a.w;
    f[4] = (__bf16)b.x; f[5] = (__bf16)b.y; f[6] = (__bf16)b.z; f[7] = (__bf16)b.w;
    *(bf16x8*)(Wob + i) = f;
}

// ------------------------------------------------- QKV per-head projections
// z=0: values -> Vt[nh][d][s] (transposed), z=1: keys -> Kws[nh][s][d],
// z=2: query -> Qws[nh][s][d] with log2(e)/32 folded into Wq.
__global__ __launch_bounds__(256) void k_proj(const float* __restrict__ vin,
                                              const float* __restrict__ kin,
                                              const float* __restrict__ qin,
                                              const float* __restrict__ Wv,
                                              const float* __restrict__ Wk,
                                              const float* __restrict__ Wq,
                                              __bf16* __restrict__ Qws,
                                              __bf16* __restrict__ Kws,
                                              __bf16* __restrict__ Vt) {
    const int z = blockIdx.z;
    const float* in = (z == 0) ? vin : ((z == 1) ? kin : qin);
    const float* W  = (z == 0) ? Wv  : ((z == 1) ? Wk  : Wq);
    const float scale = (z == 2) ? 0.04508422f : 1.0f;  // log2(e)/32
    const int bid  = blockIdx.x;
    const int nh   = bid >> 5;           // 0..63
    const int sblk = (bid & 31) << 6;    // 64 s-rows per block
    const int n = nh >> 4, h = nh & 15;
    const int lane = threadIdx.x & 63, wid = threadIdx.x >> 6;
    const int l16 = lane & 15, g = lane >> 4;

    bf16x8 Bf[4][2];
#pragma unroll
    for (int nt = 0; nt < 4; ++nt)
#pragma unroll
        for (int ks = 0; ks < 2; ++ks) {
            const float* wp = W + (nt * 16 + l16) * 64 + ks * 32 + g * 8;
            float4 a = *(const float4*)wp;
            float4 b = *(const float4*)(wp + 4);
            bf16x8 f;
            f[0] = (__bf16)(a.x * scale); f[1] = (__bf16)(a.y * scale);
            f[2] = (__bf16)(a.z * scale); f[3] = (__bf16)(a.w * scale);
            f[4] = (__bf16)(b.x * scale); f[5] = (__bf16)(b.y * scale);
            f[6] = (__bf16)(b.z * scale); f[7] = (__bf16)(b.w * scale);
            Bf[nt][ks] = f;
        }

    const int s = sblk + wid * 16 + l16;
    const float* ip = in + ((size_t)n * S_ + s) * E_ + h * 64 + g * 8;
    bf16x8 Af[2];
#pragma unroll
    for (int ks = 0; ks < 2; ++ks) {
        float4 a = *(const float4*)(ip + ks * 32);
        float4 b = *(const float4*)(ip + ks * 32 + 4);
        bf16x8 f;
        f[0] = (__bf16)a.x; f[1] = (__bf16)a.y; f[2] = (__bf16)a.z; f[3] = (__bf16)a.w;
        f[4] = (__bf16)b.x; f[5] = (__bf16)b.y; f[6] = (__bf16)b.z; f[7] = (__bf16)b.w;
        Af[ks] = f;
    }

    f32x4 acc[4];
#pragma unroll
    for (int nt = 0; nt < 4; ++nt) { acc[nt][0] = 0.f; acc[nt][1] = 0.f; acc[nt][2] = 0.f; acc[nt][3] = 0.f; }
#pragma unroll
    for (int nt = 0; nt < 4; ++nt) {
        acc[nt] = mfma16(Af[0], Bf[nt][0], acc[nt]);
        acc[nt] = mfma16(Af[1], Bf[nt][1], acc[nt]);
    }

    if (z == 0) {
#pragma unroll
        for (int nt = 0; nt < 4; ++nt)
#pragma unroll
            for (int r = 0; r < 4; ++r) {
                int e = nt * 16 + l16;
                int srow = sblk + wid * 16 + g * 4 + r;
                Vt[((size_t)nh * 64 + e) * S_ + srow] = (__bf16)acc[nt][r];
            }
    } else {
        __bf16* O = (z == 1) ? Kws : Qws;
#pragma unroll
        for (int nt = 0; nt < 4; ++nt)
#pragma unroll
            for (int r = 0; r < 4; ++r) {
                int srow = sblk + wid * 16 + g * 4 + r;
                O[((size_t)nh * S_ + srow) * 64 + nt * 16 + l16] = (__bf16)acc[nt][r];
            }
    }
}

// ----------------------------------------------------------- flash attention
// 32x32 MFMA, swapped QK^T (S^T[k][q]), softmax fully in-register:
// exp2 -> cvt_pk bf16 -> permlane32_swap redistribution -> PV B-fragment.
// No LDS, no __syncthreads in loop; K/V register-double-buffered.
__global__ __launch_bounds__(256) void k_attn(const __bf16* __restrict__ Qws,
                                              const __bf16* __restrict__ Kws,
                                              const __bf16* __restrict__ Vt,
                                              const int* __restrict__ maskp,
                                              __bf16* __restrict__ Xws) {
    const int tid = threadIdx.x, lane = tid & 63, wid = tid >> 6;
    const int l31 = lane & 31, hf = lane >> 5, h8 = hf * 8;
    // XCD swizzle: all 16 q-blocks of one (n,h) land on one XCD (bid%8 model)
    const int v = blockIdx.x;
    const int nh = (v & 7) + ((v >> 7) << 3);
    const int qb = (v >> 3) & 15;
    const int n = nh >> 4, hd = nh & 15;

    int az = 0;
    for (int i = tid; i < S_; i += 256) az |= (maskp[(size_t)n * S_ + i] == 0);
    const int anyzero = __syncthreads_or(az);

    const __bf16* Qb = Qws + (size_t)nh * S_ * 64;
    const __bf16* Kb = Kws + (size_t)nh * S_ * 64;
    const __bf16* Vb = Vt  + (size_t)nh * 64 * S_;

    const int q0 = qb * 128 + wid * 32;
    bf16x8 Qf[4];
#pragma unroll
    for (int dt = 0; dt < 4; ++dt)
        Qf[dt] = *(const bf16x8*)(Qb + (size_t)(q0 + l31) * 64 + dt * 16 + h8);

    f32x16 acc0, acc1;
#pragma unroll
    for (int i = 0; i < 16; ++i) { acc0[i] = 0.f; acc1[i] = 0.f; }
    float lsum = 0.f;

    bf16x8 KfA[2][4], VfA[2][4], KfB[2][4], VfB[2][4];

    auto loadKV = [&](bf16x8 (&Kf)[2][4], bf16x8 (&Vf)[2][4], int kb) {
        const int k0 = kb * 64;
#pragma unroll
        for (int t = 0; t < 2; ++t)
#pragma unroll
            for (int j = 0; j < 4; ++j) {
                Kf[t][j] = *(const bf16x8*)(Kb + (size_t)(k0 + t * 32 + l31) * 64 + j * 16 + h8);
                Vf[t][j] = *(const bf16x8*)(Vb + (size_t)(t * 32 + l31) * S_ + k0 + j * 16 + h8);
            }
    };

    auto body = [&](bf16x8 (&Kf)[2][4], bf16x8 (&Vf)[2][4], int kb) {
        const int k0 = kb * 64;
#pragma unroll
        for (int kt = 0; kt < 2; ++kt) {
            f32x16 s;
#pragma unroll
            for (int i = 0; i < 16; ++i) s[i] = 0.f;
#pragma unroll
            for (int dt = 0; dt < 4; ++dt) s = mfma32(Kf[kt][dt], Qf[dt], s);
            if (anyzero) {
#pragma unroll
                for (int r = 0; r < 16; ++r) {
                    int kk = k0 + kt * 32 + (r & 3) + 8 * (r >> 2) + 4 * hf;
                    if (maskp[(size_t)n * S_ + kk] == 0) s[r] = -1e30f;
                }
            }
            float p[16];
#pragma unroll
            for (int r = 0; r < 16; ++r) p[r] = __builtin_amdgcn_exp2f(s[r]);
            lsum += ((((p[0] + p[1]) + (p[2] + p[3])) + ((p[4] + p[5]) + (p[6] + p[7])))
                   + (((p[8] + p[9]) + (p[10] + p[11])) + ((p[12] + p[13]) + (p[14] + p[15]))));
            u32 w0 = pack2(p[0],  p[1]),  w1 = pack2(p[2],  p[3]);
            u32 w2 = pack2(p[4],  p[5]),  w3 = pack2(p[6],  p[7]);
            u32 w4 = pack2(p[8],  p[9]),  w5 = pack2(p[10], p[11]);
            u32 w6 = pack2(p[12], p[13]), w7 = pack2(p[14], p[15]);
            swap32(w0, w2); swap32(w1, w3); swap32(w4, w6); swap32(w5, w7);
            u32x4 t0; t0[0] = w0; t0[1] = w1; t0[2] = w2; t0[3] = w3;
            u32x4 t1; t1[0] = w4; t1[1] = w5; t1[2] = w6; t1[3] = w7;
            bf16x8 P0 = __builtin_bit_cast(bf16x8, t0);
            bf16x8 P1 = __builtin_bit_cast(bf16x8, t1);
            acc0 = mfma32(Vf[0][kt * 2],     P0, acc0);
            acc0 = mfma32(Vf[0][kt * 2 + 1], P1, acc0);
            acc1 = mfma32(Vf[1][kt * 2],     P0, acc1);
            acc1 = mfma32(Vf[1][kt * 2 + 1], P1, acc1);
        }
    };

    loadKV(KfA, VfA, 0);
    for (int kb = 0; kb < 32; kb += 2) {
        loadKV(KfB, VfB, kb + 1);
        body(KfA, VfA, kb);
        loadKV(KfA, VfA, (kb + 2) & 31);  // last iter wraps: harmless reload
        body(KfB, VfB, kb + 1);
    }

    lsum += __shfl_xor(lsum, 32);
    const float inv = 1.0f / lsum;
    const int qg = q0 + l31;
    __bf16* Ob = Xws + ((size_t)(n * S_ + qg)) * E_ + hd * 64;

    auto store_half = [&](const f32x16& a, int dv) {
#pragma unroll
        for (int rr = 0; rr < 4; ++rr) {
            bf16x4 o;
#pragma unroll
            for (int j = 0; j < 4; ++j) o[j] = (__bf16)(a[rr * 4 + j] * inv);
            *(bf16x4*)(Ob + dv * 32 + rr * 8 + hf * 4) = o;
        }
    };
    store_half(acc0, 0);
    store_half(acc1, 1);
}

// ------------------------------------------------------- output GEMM + bias
// Y[m][o] = sum_e X[m][e] * Wo[o][e] + bo[o];  M=8192, N=1024, K=1024
// 32x32 MFMA; per wave 32m x 64o; block 128m x 64o.
__global__ __launch_bounds__(256) void k_out(const __bf16* __restrict__ Xws,
                                             const __bf16* __restrict__ Wob,
                                             const float* __restrict__ bo,
                                             float* __restrict__ out) {
    const int lane = threadIdx.x & 63, wid = threadIdx.x >> 6;
    const int l31 = lane & 31, hf = lane >> 5, h8 = hf * 8;
    const int mb = blockIdx.x >> 4, ob = blockIdx.x & 15;
    const int m0 = mb * 128 + wid * 32, o0 = ob * 64;

    f32x16 acc0, acc1;
#pragma unroll
    for (int i = 0; i < 16; ++i) { acc0[i] = 0.f; acc1[i] = 0.f; }

    const __bf16* Xp = Xws + (size_t)(m0 + l31) * E_ + h8;
    const __bf16* W0 = Wob + (size_t)(o0 + l31) * E_ + h8;
    const __bf16* W1 = W0 + (size_t)32 * E_;

#pragma unroll 4
    for (int ks = 0; ks < 64; ++ks) {
        bf16x8 A = *(const bf16x8*)(Xp + ks * 16);
        acc0 = mfma32(A, *(const bf16x8*)(W0 + ks * 16), acc0);
        acc1 = mfma32(A, *(const bf16x8*)(W1 + ks * 16), acc1);
    }

    const float b0 = bo[o0 + l31], b1 = bo[o0 + 32 + l31];
#pragma unroll
    for (int rr = 0; rr < 4; ++rr)
#pragma unroll
        for (int j = 0; j < 4; ++j) {
            size_t m = (size_t)m0 + rr * 8 + hf * 4 + j;
            out[m * E_ + o0 + l31]      = acc0[rr * 4 + j] + b0;
            out[m * E_ + o0 + 32 + l31] = acc1[rr * 4 + j] + b1;
        }
}

extern "C" void kernel_launch(void* const* d_in, const int* in_sizes, int n_in,
                              void* d_out, int out_size, void* d_ws, size_t ws_size,
                              hipStream_t stream) {
    const float* vin  = (const float*)d_in[0];
    const float* kin  = (const float*)d_in[1];
    const float* qin  = (const float*)d_in[2];
    const int*   mask = (const int*)d_in[3];
    const float* Wv   = (const float*)d_in[4];
    const float* Wk   = (const float*)d_in[5];
    const float* Wq   = (const float*)d_in[6];
    const float* Wo   = (const float*)d_in[7];
    const float* bo   = (const float*)d_in[8];

    __bf16* Qws = (__bf16*)d_ws;                       // [64][2048][64]
    __bf16* Kws = Qws + (size_t)NH_ * S_ * 64;         // [64][2048][64]
    __bf16* Vt  = Kws + (size_t)NH_ * S_ * 64;         // [64][64][2048]
    __bf16* Xws = Vt  + (size_t)NH_ * S_ * 64;         // [4][2048][1024]
    __bf16* Wob = Xws + (size_t)4 * S_ * E_;           // [1024][1024]
    float* out = (float*)d_out;

    hipLaunchKernelGGL(k_cast_wo, dim3(512), dim3(256), 0, stream, Wo, Wob);
    hipLaunchKernelGGL(k_proj, dim3(2048, 1, 3), dim3(256), 0, stream,
                       vin, kin, qin, Wv, Wk, Wq, Qws, Kws, Vt);
    hipLaunchKernelGGL(k_attn, dim3(1024), dim3(256), 0, stream, Qws, Kws, Vt, mask, Xws);
    hipLaunchKernelGGL(k_out, dim3(1024), dim3(256), 0, stream, Xws, Wob, bo, out);
}

// Round 3
// 289.040 us; speedup vs baseline: 1.5095x; 1.4095x over previous
//
#include <hip/hip_runtime.h>
#include <hip/hip_bf16.h>

typedef __bf16 bf16x8 __attribute__((ext_vector_type(8)));
typedef __bf16 bf16x4 __attribute__((ext_vector_type(4)));
typedef __bf16 bf16x2 __attribute__((ext_vector_type(2)));
typedef float  f32x4  __attribute__((ext_vector_type(4)));
typedef float  f32x16 __attribute__((ext_vector_type(16)));
typedef unsigned int u32;
typedef u32 u32x4 __attribute__((ext_vector_type(4)));

#define S_  2048
#define E_  1024
#define NH_ 64

__device__ __forceinline__ f32x4 mfma16(bf16x8 a, bf16x8 b, f32x4 c) {
    return __builtin_amdgcn_mfma_f32_16x16x32_bf16(a, b, c, 0, 0, 0);
}
__device__ __forceinline__ f32x16 mfma32(bf16x8 a, bf16x8 b, f32x16 c) {
    return __builtin_amdgcn_mfma_f32_32x32x16_bf16(a, b, c, 0, 0, 0);
}
__device__ __forceinline__ u32 pack2(float a, float b) {
    bf16x2 t; t[0] = (__bf16)a; t[1] = (__bf16)b;
    return __builtin_bit_cast(u32, t);
}
__device__ __forceinline__ void swap32(u32& a, u32& b) {
    asm("v_permlane32_swap_b32 %0, %1" : "+v"(a), "+v"(b));
}
__device__ __forceinline__ f32x16 zero16() {
    f32x16 z;
#pragma unroll
    for (int i = 0; i < 16; ++i) z[i] = 0.f;
    return z;
}
// async global->LDS, 16B per lane; lds dest must be wave-uniform base (+lane*16 implicit)
__device__ __forceinline__ void gload_lds16(const void* g, void* l) {
    __builtin_amdgcn_global_load_lds(
        (const __attribute__((address_space(1))) unsigned int*)g,
        (__attribute__((address_space(3))) unsigned int*)l, 16, 0, 0);
}

// ---------------------------------------------------------------- Wo -> bf16
__global__ __launch_bounds__(256) void k_cast_wo(const float* __restrict__ Wo,
                                                 __bf16* __restrict__ Wob) {
    int i = (blockIdx.x * 256 + threadIdx.x) * 8;
    float4 a = *(const float4*)(Wo + i);
    float4 b = *(const float4*)(Wo + i + 4);
    bf16x8 f;
    f[0] = (__bf16)a.x; f[1] = (__bf16)a.y; f[2] = (__bf16)a.z; f[3] = (__bf16)a.w;
    f[4] = (__bf16)b.x; f[5] = (__bf16)b.y; f[6] = (__bf16)b.z; f[7] = (__bf16)b.w;
    *(bf16x8*)(Wob + i) = f;
}

// ------------------------------------------------- QKV per-head projections
// z=0: values -> Vt[nh][d][s^((d&7)<<3)]  (transposed + XOR-swizzled cols)
// z=1: keys   -> Kws[nh][s][e^((s&7)<<3)] (XOR-swizzled cols)
// z=2: query  -> Qws[nh][s][e] plain, with log2(e)/32 folded into Wq.
__global__ __launch_bounds__(256) void k_proj(const float* __restrict__ vin,
                                              const float* __restrict__ kin,
                                              const float* __restrict__ qin,
                                              const float* __restrict__ Wv,
                                              const float* __restrict__ Wk,
                                              const float* __restrict__ Wq,
                                              __bf16* __restrict__ Qws,
                                              __bf16* __restrict__ Kws,
                                              __bf16* __restrict__ Vt) {
    const int z = blockIdx.z;
    const float* in = (z == 0) ? vin : ((z == 1) ? kin : qin);
    const float* W  = (z == 0) ? Wv  : ((z == 1) ? Wk  : Wq);
    const float scale = (z == 2) ? 0.04508422f : 1.0f;  // log2(e)/32
    const int bid  = blockIdx.x;
    const int nh   = bid >> 5;
    const int sblk = (bid & 31) << 6;
    const int n = nh >> 4, h = nh & 15;
    const int lane = threadIdx.x & 63, wid = threadIdx.x >> 6;
    const int l16 = lane & 15, g = lane >> 4;

    bf16x8 Bf[4][2];
#pragma unroll
    for (int nt = 0; nt < 4; ++nt)
#pragma unroll
        for (int ks = 0; ks < 2; ++ks) {
            const float* wp = W + (nt * 16 + l16) * 64 + ks * 32 + g * 8;
            float4 a = *(const float4*)wp;
            float4 b = *(const float4*)(wp + 4);
            bf16x8 f;
            f[0] = (__bf16)(a.x * scale); f[1] = (__bf16)(a.y * scale);
            f[2] = (__bf16)(a.z * scale); f[3] = (__bf16)(a.w * scale);
            f[4] = (__bf16)(b.x * scale); f[5] = (__bf16)(b.y * scale);
            f[6] = (__bf16)(b.z * scale); f[7] = (__bf16)(b.w * scale);
            Bf[nt][ks] = f;
        }

    const int s = sblk + wid * 16 + l16;
    const float* ip = in + ((size_t)n * S_ + s) * E_ + h * 64 + g * 8;
    bf16x8 Af[2];
#pragma unroll
    for (int ks = 0; ks < 2; ++ks) {
        float4 a = *(const float4*)(ip + ks * 32);
        float4 b = *(const float4*)(ip + ks * 32 + 4);
        bf16x8 f;
        f[0] = (__bf16)a.x; f[1] = (__bf16)a.y; f[2] = (__bf16)a.z; f[3] = (__bf16)a.w;
        f[4] = (__bf16)b.x; f[5] = (__bf16)b.y; f[6] = (__bf16)b.z; f[7] = (__bf16)b.w;
        Af[ks] = f;
    }

    f32x4 acc[4];
#pragma unroll
    for (int nt = 0; nt < 4; ++nt) { acc[nt][0] = 0.f; acc[nt][1] = 0.f; acc[nt][2] = 0.f; acc[nt][3] = 0.f; }
#pragma unroll
    for (int nt = 0; nt < 4; ++nt) {
        acc[nt] = mfma16(Af[0], Bf[nt][0], acc[nt]);
        acc[nt] = mfma16(Af[1], Bf[nt][1], acc[nt]);
    }

    if (z == 0) {
#pragma unroll
        for (int nt = 0; nt < 4; ++nt)
#pragma unroll
            for (int r = 0; r < 4; ++r) {
                int e = nt * 16 + l16;
                int srow = sblk + wid * 16 + g * 4 + r;
                int sc = srow ^ ((e & 7) << 3);   // V col swizzle
                Vt[((size_t)nh * 64 + e) * S_ + sc] = (__bf16)acc[nt][r];
            }
    } else if (z == 1) {
#pragma unroll
        for (int nt = 0; nt < 4; ++nt)
#pragma unroll
            for (int r = 0; r < 4; ++r) {
                int srow = sblk + wid * 16 + g * 4 + r;
                int ec = (nt * 16 + l16) ^ ((srow & 7) << 3);  // K col swizzle
                Kws[((size_t)nh * S_ + srow) * 64 + ec] = (__bf16)acc[nt][r];
            }
    } else {
#pragma unroll
        for (int nt = 0; nt < 4; ++nt)
#pragma unroll
            for (int r = 0; r < 4; ++r) {
                int srow = sblk + wid * 16 + g * 4 + r;
                Qws[((size_t)nh * S_ + srow) * 64 + nt * 16 + l16] = (__bf16)acc[nt][r];
            }
    }
}

// ----------------------------------------------------------- flash attention
// Block: 4 waves x 64 q = 256 q, one (n,h). K/V tiles (64k x 64d each, 8KB+8KB)
// staged once per block via global_load_lds into double-buffered LDS (2-phase
// pipeline, one __syncthreads per tile). Fragments ds_read_b128 with XOR
// swizzle (pre-applied in global by k_proj). Softmax in-register
// (exp2 -> cvt_pk -> permlane32_swap), no LDS roundtrip for P.
__global__ __launch_bounds__(256) void k_attn(const __bf16* __restrict__ Qws,
                                              const __bf16* __restrict__ Kws,
                                              const __bf16* __restrict__ Vt,
                                              const int* __restrict__ maskp,
                                              __bf16* __restrict__ Xws) {
    __shared__ __align__(16) char lds[2][16384];  // [buf][K 8KB | V 8KB]
    const int tid = threadIdx.x, lane = tid & 63, wid = tid >> 6;
    const int l31 = lane & 31, hf = lane >> 5, h8 = hf * 8;
    // XCD swizzle: XCD x gets nh in [8x, 8x+8) (K/V working set = 4MB = one L2)
    const int v = blockIdx.x;             // 512 blocks = 64 nh x 8 qb
    const int u = v >> 3;
    const int nh = (v & 7) * 8 + (u >> 3), qb = u & 7;
    const int n = nh >> 4, hd = nh & 15;

    int az = 0;
    for (int i = tid; i < S_; i += 256) az |= (maskp[(size_t)n * S_ + i] == 0);
    const int anyzero = __syncthreads_or(az);

    const char* Kc = (const char*)(Kws + (size_t)nh * S_ * 64);
    const char* Vc = (const char*)(Vt  + (size_t)nh * 64 * S_);
    const __bf16* Qb = Qws + (size_t)nh * S_ * 64;

    const int q0 = qb * 256 + wid * 64;
    bf16x8 QfA[4], QfB[4];
#pragma unroll
    for (int dt = 0; dt < 4; ++dt) {
        QfA[dt] = *(const bf16x8*)(Qb + (size_t)(q0 + l31) * 64 + dt * 16 + h8);
        QfB[dt] = *(const bf16x8*)(Qb + (size_t)(q0 + 32 + l31) * 64 + dt * 16 + h8);
    }

    f32x16 accA0 = zero16(), accA1 = zero16(), accB0 = zero16(), accB1 = zero16();
    float lsum0 = 0.f, lsum1 = 0.f;

    // stage K/V tile kb into buf; each wave copies 2KB of K + 2KB of V
    auto stage = [&](int buf, int kb) {
        char* base = &lds[buf][0];
        const char* ks = Kc + (size_t)kb * 8192 + wid * 2048 + lane * 16;
        char* kd = base + wid * 2048;
        gload_lds16(ks, kd);
        gload_lds16(ks + 1024, kd + 1024);
        const int r0 = wid * 16 + (lane >> 3);
        const char* vs = Vc + (size_t)r0 * (S_ * 2) + (size_t)kb * 128 + (lane & 7) * 16;
        char* vd = base + 8192 + wid * 2048;
        gload_lds16(vs, vd);
        gload_lds16(vs + (size_t)8 * (S_ * 2), vd + 1024);
    };

    const int swz = (l31 & 7) << 4;
    auto softmax = [&](const f32x16& s, float& ls, int kbase, bf16x8& P0, bf16x8& P1) {
        f32x16 sv = s;
        if (anyzero) {
#pragma unroll
            for (int r = 0; r < 16; ++r) {
                int kk = kbase + (r & 3) + 8 * (r >> 2) + 4 * hf;
                if (maskp[(size_t)n * S_ + kk] == 0) sv[r] = -1e30f;
            }
        }
        float p[16];
#pragma unroll
        for (int r = 0; r < 16; ++r) p[r] = __builtin_amdgcn_exp2f(sv[r]);
        ls += ((((p[0] + p[1]) + (p[2] + p[3])) + ((p[4] + p[5]) + (p[6] + p[7])))
            + (((p[8] + p[9]) + (p[10] + p[11])) + ((p[12] + p[13]) + (p[14] + p[15]))));
        u32 w0 = pack2(p[0],  p[1]),  w1 = pack2(p[2],  p[3]);
        u32 w2 = pack2(p[4],  p[5]),  w3 = pack2(p[6],  p[7]);
        u32 w4 = pack2(p[8],  p[9]),  w5 = pack2(p[10], p[11]);
        u32 w6 = pack2(p[12], p[13]), w7 = pack2(p[14], p[15]);
        swap32(w0, w2); swap32(w1, w3); swap32(w4, w6); swap32(w5, w7);
        u32x4 t0; t0[0] = w0; t0[1] = w1; t0[2] = w2; t0[3] = w3;
        u32x4 t1; t1[0] = w4; t1[1] = w5; t1[2] = w6; t1[3] = w7;
        P0 = __builtin_bit_cast(bf16x8, t0);
        P1 = __builtin_bit_cast(bf16x8, t1);
    };

    stage(0, 0);
    int buf = 0;
    for (int kb = 0; kb < 32; ++kb) {
        __syncthreads();                       // staging of `buf` complete
        if (kb < 31) stage(buf ^ 1, kb + 1);   // prefetch next tile
        char* base = &lds[buf][0];
        char* vbase = base + 8192;
        const int k0 = kb * 64;
#pragma unroll
        for (int kt = 0; kt < 2; ++kt) {
            // K fragments: rows kt*32+l31, d-slice dt (swizzled)
            bf16x8 K0 = *(const bf16x8*)(base + (kt * 32 + l31) * 128 + (((0 * 2 + hf) * 16) ^ swz));
            bf16x8 K1 = *(const bf16x8*)(base + (kt * 32 + l31) * 128 + (((1 * 2 + hf) * 16) ^ swz));
            bf16x8 K2 = *(const bf16x8*)(base + (kt * 32 + l31) * 128 + (((2 * 2 + hf) * 16) ^ swz));
            bf16x8 K3 = *(const bf16x8*)(base + (kt * 32 + l31) * 128 + (((3 * 2 + hf) * 16) ^ swz));
            f32x16 sA = zero16(), sB = zero16();
            sA = mfma32(K0, QfA[0], sA); sA = mfma32(K1, QfA[1], sA);
            sA = mfma32(K2, QfA[2], sA); sA = mfma32(K3, QfA[3], sA);
            sB = mfma32(K0, QfB[0], sB); sB = mfma32(K1, QfB[1], sB);
            sB = mfma32(K2, QfB[2], sB); sB = mfma32(K3, QfB[3], sB);
            bf16x8 PA0, PA1, PB0, PB1;
            softmax(sA, lsum0, k0 + kt * 32, PA0, PA1);
            softmax(sB, lsum1, k0 + kt * 32, PB0, PB1);
            // V fragments: d-rows vt*32+l31, k-slice kt*2+{0,1} (swizzled)
            bf16x8 V00 = *(const bf16x8*)(vbase + (0 * 32 + l31) * 128 + ((((kt * 2 + 0) * 2 + hf) * 16) ^ swz));
            bf16x8 V01 = *(const bf16x8*)(vbase + (0 * 32 + l31) * 128 + ((((kt * 2 + 1) * 2 + hf) * 16) ^ swz));
            bf16x8 V10 = *(const bf16x8*)(vbase + (1 * 32 + l31) * 128 + ((((kt * 2 + 0) * 2 + hf) * 16) ^ swz));
            bf16x8 V11 = *(const bf16x8*)(vbase + (1 * 32 + l31) * 128 + ((((kt * 2 + 1) * 2 + hf) * 16) ^ swz));
            accA0 = mfma32(V00, PA0, accA0); accA0 = mfma32(V01, PA1, accA0);
            accA1 = mfma32(V10, PA0, accA1); accA1 = mfma32(V11, PA1, accA1);
            accB0 = mfma32(V00, PB0, accB0); accB0 = mfma32(V01, PB1, accB0);
            accB1 = mfma32(V10, PB0, accB1); accB1 = mfma32(V11, PB1, accB1);
        }
        buf ^= 1;
    }

    lsum0 += __shfl_xor(lsum0, 32);
    lsum1 += __shfl_xor(lsum1, 32);
    const float inv0 = 1.0f / lsum0, inv1 = 1.0f / lsum1;

    auto store_half = [&](const f32x16& a, int qg, int dv, float inv) {
        __bf16* Ob = Xws + ((size_t)(n * S_ + qg)) * E_ + hd * 64;
#pragma unroll
        for (int rr = 0; rr < 4; ++rr) {
            bf16x4 o;
#pragma unroll
            for (int j = 0; j < 4; ++j) o[j] = (__bf16)(a[rr * 4 + j] * inv);
            *(bf16x4*)(Ob + dv * 32 + rr * 8 + hf * 4) = o;
        }
    };
    store_half(accA0, q0 + l31, 0, inv0);
    store_half(accA1, q0 + l31, 1, inv0);
    store_half(accB0, q0 + 32 + l31, 0, inv1);
    store_half(accB1, q0 + 32 + l31, 1, inv1);
}

// ------------------------------------------------------- output GEMM + bias
__global__ __launch_bounds__(256) void k_out(const __bf16* __restrict__ Xws,
                                             const __bf16* __restrict__ Wob,
                                             const float* __restrict__ bo,
                                             float* __restrict__ out) {
    const int lane = threadIdx.x & 63, wid = threadIdx.x >> 6;
    const int l31 = lane & 31, hf = lane >> 5, h8 = hf * 8;
    const int mb = blockIdx.x >> 4, ob = blockIdx.x & 15;
    const int m0 = mb * 128 + wid * 32, o0 = ob * 64;

    f32x16 acc0 = zero16(), acc1 = zero16();

    const __bf16* Xp = Xws + (size_t)(m0 + l31) * E_ + h8;
    const __bf16* W0 = Wob + (size_t)(o0 + l31) * E_ + h8;
    const __bf16* W1 = W0 + (size_t)32 * E_;

#pragma unroll 4
    for (int ks = 0; ks < 64; ++ks) {
        bf16x8 A = *(const bf16x8*)(Xp + ks * 16);
        acc0 = mfma32(A, *(const bf16x8*)(W0 + ks * 16), acc0);
        acc1 = mfma32(A, *(const bf16x8*)(W1 + ks * 16), acc1);
    }

    const float b0 = bo[o0 + l31], b1 = bo[o0 + 32 + l31];
#pragma unroll
    for (int rr = 0; rr < 4; ++rr)
#pragma unroll
        for (int j = 0; j < 4; ++j) {
            size_t m = (size_t)m0 + rr * 8 + hf * 4 + j;
            out[m * E_ + o0 + l31]      = acc0[rr * 4 + j] + b0;
            out[m * E_ + o0 + 32 + l31] = acc1[rr * 4 + j] + b1;
        }
}

extern "C" void kernel_launch(void* const* d_in, const int* in_sizes, int n_in,
                              void* d_out, int out_size, void* d_ws, size_t ws_size,
                              hipStream_t stream) {
    const float* vin  = (const float*)d_in[0];
    const float* kin  = (const float*)d_in[1];
    const float* qin  = (const float*)d_in[2];
    const int*   mask = (const int*)d_in[3];
    const float* Wv   = (const float*)d_in[4];
    const float* Wk   = (const float*)d_in[5];
    const float* Wq   = (const float*)d_in[6];
    const float* Wo   = (const float*)d_in[7];
    const float* bo   = (const float*)d_in[8];

    __bf16* Qws = (__bf16*)d_ws;                       // [64][2048][64]
    __bf16* Kws = Qws + (size_t)NH_ * S_ * 64;         // [64][2048][64] swizzled
    __bf16* Vt  = Kws + (size_t)NH_ * S_ * 64;         // [64][64][2048] swizzled
    __bf16* Xws = Vt  + (size_t)NH_ * S_ * 64;         // [4][2048][1024]
    __bf16* Wob = Xws + (size_t)4 * S_ * E_;           // [1024][1024]
    float* out = (float*)d_out;

    hipLaunchKernelGGL(k_cast_wo, dim3(512), dim3(256), 0, stream, Wo, Wob);
    hipLaunchKernelGGL(k_proj, dim3(2048, 1, 3), dim3(256), 0, stream,
                       vin, kin, qin, Wv, Wk, Wq, Qws, Kws, Vt);
    hipLaunchKernelGGL(k_attn, dim3(512), dim3(256), 0, stream, Qws, Kws, Vt, mask, Xws);
    hipLaunchKernelGGL(k_out, dim3(1024), dim3(256), 0, stream, Xws, Wob, bo, out);
}

// Round 4
// 235.527 us; speedup vs baseline: 1.8525x; 1.2272x over previous
//
#include <hip/hip_runtime.h>
#include <hip/hip_bf16.h>

typedef __bf16 bf16x8 __attribute__((ext_vector_type(8)));
typedef __bf16 bf16x4 __attribute__((ext_vector_type(4)));
typedef __bf16 bf16x2 __attribute__((ext_vector_type(2)));
typedef float  f32x4  __attribute__((ext_vector_type(4)));
typedef float  f32x16 __attribute__((ext_vector_type(16)));
typedef unsigned int u32;
typedef u32 u32x4 __attribute__((ext_vector_type(4)));

#define S_  2048
#define E_  1024
#define NH_ 64

__device__ __forceinline__ f32x4 mfma16(bf16x8 a, bf16x8 b, f32x4 c) {
    return __builtin_amdgcn_mfma_f32_16x16x32_bf16(a, b, c, 0, 0, 0);
}
__device__ __forceinline__ f32x16 mfma32(bf16x8 a, bf16x8 b, f32x16 c) {
    return __builtin_amdgcn_mfma_f32_32x32x16_bf16(a, b, c, 0, 0, 0);
}
__device__ __forceinline__ u32 pack2(float a, float b) {
    bf16x2 t; t[0] = (__bf16)a; t[1] = (__bf16)b;
    return __builtin_bit_cast(u32, t);
}
__device__ __forceinline__ void swap32(u32& a, u32& b) {
    asm("v_permlane32_swap_b32 %0, %1" : "+v"(a), "+v"(b));
}
__device__ __forceinline__ f32x16 zero16() {
    f32x16 z;
#pragma unroll
    for (int i = 0; i < 16; ++i) z[i] = 0.f;
    return z;
}
__device__ __forceinline__ void gload_lds16(const void* g, void* l) {
    __builtin_amdgcn_global_load_lds(
        (const __attribute__((address_space(1))) unsigned int*)g,
        (__attribute__((address_space(3))) unsigned int*)l, 16, 0, 0);
}

// ---------------------------------------------------------------- Wo -> bf16
__global__ __launch_bounds__(256) void k_cast_wo(const float* __restrict__ Wo,
                                                 __bf16* __restrict__ Wob) {
    int i = (blockIdx.x * 256 + threadIdx.x) * 8;
    float4 a = *(const float4*)(Wo + i);
    float4 b = *(const float4*)(Wo + i + 4);
    bf16x8 f;
    f[0] = (__bf16)a.x; f[1] = (__bf16)a.y; f[2] = (__bf16)a.z; f[3] = (__bf16)a.w;
    f[4] = (__bf16)b.x; f[5] = (__bf16)b.y; f[6] = (__bf16)b.z; f[7] = (__bf16)b.w;
    *(bf16x8*)(Wob + i) = f;
}

// ------------------------------------------------- QKV per-head projections
// z=0: values -> Vt[nh][d][s^((d&7)<<3)]  (transposed via SWAPPED mfma operands
//      so e lands in the reg dim and s in the lane dim -> coalesced stores)
// z=1: keys   -> Kws[nh][s][e^((s&7)<<3)] (XOR-swizzled cols)
// z=2: query  -> Qws[nh][s][e] plain, with log2(e)/32 folded into Wq.
__global__ __launch_bounds__(256) void k_proj(const float* __restrict__ vin,
                                              const float* __restrict__ kin,
                                              const float* __restrict__ qin,
                                              const float* __restrict__ Wv,
                                              const float* __restrict__ Wk,
                                              const float* __restrict__ Wq,
                                              __bf16* __restrict__ Qws,
                                              __bf16* __restrict__ Kws,
                                              __bf16* __restrict__ Vt) {
    const int z = blockIdx.z;
    const float* in = (z == 0) ? vin : ((z == 1) ? kin : qin);
    const float* W  = (z == 0) ? Wv  : ((z == 1) ? Wk  : Wq);
    const float scale = (z == 2) ? 0.04508422f : 1.0f;  // log2(e)/32
    const int bid  = blockIdx.x;
    const int nh   = bid >> 5;
    const int sblk = (bid & 31) << 6;
    const int n = nh >> 4, h = nh & 15;
    const int lane = threadIdx.x & 63, wid = threadIdx.x >> 6;
    const int l16 = lane & 15, g = lane >> 4;

    bf16x8 Bf[4][2];
#pragma unroll
    for (int nt = 0; nt < 4; ++nt)
#pragma unroll
        for (int ks = 0; ks < 2; ++ks) {
            const float* wp = W + (nt * 16 + l16) * 64 + ks * 32 + g * 8;
            float4 a = *(const float4*)wp;
            float4 b = *(const float4*)(wp + 4);
            bf16x8 f;
            f[0] = (__bf16)(a.x * scale); f[1] = (__bf16)(a.y * scale);
            f[2] = (__bf16)(a.z * scale); f[3] = (__bf16)(a.w * scale);
            f[4] = (__bf16)(b.x * scale); f[5] = (__bf16)(b.y * scale);
            f[6] = (__bf16)(b.z * scale); f[7] = (__bf16)(b.w * scale);
            Bf[nt][ks] = f;
        }

    const int s = sblk + wid * 16 + l16;
    const float* ip = in + ((size_t)n * S_ + s) * E_ + h * 64 + g * 8;
    bf16x8 Af[2];
#pragma unroll
    for (int ks = 0; ks < 2; ++ks) {
        float4 a = *(const float4*)(ip + ks * 32);
        float4 b = *(const float4*)(ip + ks * 32 + 4);
        bf16x8 f;
        f[0] = (__bf16)a.x; f[1] = (__bf16)a.y; f[2] = (__bf16)a.z; f[3] = (__bf16)a.w;
        f[4] = (__bf16)b.x; f[5] = (__bf16)b.y; f[6] = (__bf16)b.z; f[7] = (__bf16)b.w;
        Af[ks] = f;
    }

    f32x4 acc[4];
#pragma unroll
    for (int nt = 0; nt < 4; ++nt) { acc[nt][0] = 0.f; acc[nt][1] = 0.f; acc[nt][2] = 0.f; acc[nt][3] = 0.f; }

    if (z == 0) {
        // swapped operands: D[row(reg)=e within nt-block][col(lane)=s]
#pragma unroll
        for (int nt = 0; nt < 4; ++nt) {
            acc[nt] = mfma16(Bf[nt][0], Af[0], acc[nt]);
            acc[nt] = mfma16(Bf[nt][1], Af[1], acc[nt]);
        }
#pragma unroll
        for (int nt = 0; nt < 4; ++nt)
#pragma unroll
            for (int r = 0; r < 4; ++r) {
                int e = nt * 16 + g * 4 + r;
                int srow = sblk + wid * 16 + l16;
                int sc = srow ^ ((e & 7) << 3);   // V col swizzle (lane-contig within 32B)
                Vt[((size_t)nh * 64 + e) * S_ + sc] = (__bf16)acc[nt][r];
            }
    } else {
#pragma unroll
        for (int nt = 0; nt < 4; ++nt) {
            acc[nt] = mfma16(Af[0], Bf[nt][0], acc[nt]);
            acc[nt] = mfma16(Af[1], Bf[nt][1], acc[nt]);
        }
        if (z == 1) {
#pragma unroll
            for (int nt = 0; nt < 4; ++nt)
#pragma unroll
                for (int r = 0; r < 4; ++r) {
                    int srow = sblk + wid * 16 + g * 4 + r;
                    int ec = (nt * 16 + l16) ^ ((srow & 7) << 3);  // K col swizzle
                    Kws[((size_t)nh * S_ + srow) * 64 + ec] = (__bf16)acc[nt][r];
                }
        } else {
#pragma unroll
            for (int nt = 0; nt < 4; ++nt)
#pragma unroll
                for (int r = 0; r < 4; ++r) {
                    int srow = sblk + wid * 16 + g * 4 + r;
                    Qws[((size_t)nh * S_ + srow) * 64 + nt * 16 + l16] = (__bf16)acc[nt][r];
                }
        }
    }
}

// ----------------------------------------------------------- flash attention
// Block: 4 waves x 32 q = 128 q, one (n,h); grid 1024 = 4 blocks/CU.
// K/V tiles (64k x 64d, 8KB+8KB) double-buffered via global_load_lds, one
// __syncthreads per tile. ds_read_b128 with XOR swizzle (pre-applied in
// global). Softmax in-register (exp2 -> cvt_pk -> permlane32_swap).
__global__ __launch_bounds__(256, 4) void k_attn(const __bf16* __restrict__ Qws,
                                                 const __bf16* __restrict__ Kws,
                                                 const __bf16* __restrict__ Vt,
                                                 const int* __restrict__ maskp,
                                                 __bf16* __restrict__ Xws) {
    __shared__ __align__(16) char lds[2][16384];  // [buf][K 8KB | V 8KB]
    const int tid = threadIdx.x, lane = tid & 63, wid = tid >> 6;
    const int l31 = lane & 31, hf = lane >> 5, h8 = hf * 8;
    // XCD swizzle: XCD x gets nh in [8x, 8x+8); 1024 blocks = 64 nh x 16 qb
    const int v = blockIdx.x;
    const int u = v >> 3;
    const int nh = (v & 7) * 8 + (u & 7), qb = u >> 3;
    const int n = nh >> 4, hd = nh & 15;

    int az = 0;
    for (int i = tid; i < S_; i += 256) az |= (maskp[(size_t)n * S_ + i] == 0);
    const int anyzero = __syncthreads_or(az);

    const char* Kc = (const char*)(Kws + (size_t)nh * S_ * 64);
    const char* Vc = (const char*)(Vt  + (size_t)nh * 64 * S_);
    const __bf16* Qb = Qws + (size_t)nh * S_ * 64;

    const int q0 = qb * 128 + wid * 32;
    bf16x8 Qf[4];
#pragma unroll
    for (int dt = 0; dt < 4; ++dt)
        Qf[dt] = *(const bf16x8*)(Qb + (size_t)(q0 + l31) * 64 + dt * 16 + h8);

    f32x16 acc0 = zero16(), acc1 = zero16();
    float lsum = 0.f;

    auto stage = [&](int buf, int kb) {
        char* base = &lds[buf][0];
        const char* ks = Kc + (size_t)kb * 8192 + wid * 2048 + lane * 16;
        char* kd = base + wid * 2048;
        gload_lds16(ks, kd);
        gload_lds16(ks + 1024, kd + 1024);
        const int r0 = wid * 16 + (lane >> 3);
        const char* vs = Vc + (size_t)r0 * (S_ * 2) + (size_t)kb * 128 + (lane & 7) * 16;
        char* vd = base + 8192 + wid * 2048;
        gload_lds16(vs, vd);
        gload_lds16(vs + (size_t)8 * (S_ * 2), vd + 1024);
    };

    const int swz = (l31 & 7) << 4;

    stage(0, 0);
    int buf = 0;
    for (int kb = 0; kb < 32; ++kb) {
        __syncthreads();                       // staging of `buf` complete
        if (kb < 31) stage(buf ^ 1, kb + 1);   // prefetch next tile (drains at next barrier)
        char* base = &lds[buf][0];
        char* vbase = base + 8192;
        const int k0 = kb * 64;
#pragma unroll
        for (int kt = 0; kt < 2; ++kt) {
            bf16x8 K0 = *(const bf16x8*)(base + (kt * 32 + l31) * 128 + (((0 * 2 + hf) * 16) ^ swz));
            bf16x8 K1 = *(const bf16x8*)(base + (kt * 32 + l31) * 128 + (((1 * 2 + hf) * 16) ^ swz));
            bf16x8 K2 = *(const bf16x8*)(base + (kt * 32 + l31) * 128 + (((2 * 2 + hf) * 16) ^ swz));
            bf16x8 K3 = *(const bf16x8*)(base + (kt * 32 + l31) * 128 + (((3 * 2 + hf) * 16) ^ swz));
            __builtin_amdgcn_s_setprio(1);
            f32x16 s = zero16();
            s = mfma32(K0, Qf[0], s); s = mfma32(K1, Qf[1], s);
            s = mfma32(K2, Qf[2], s); s = mfma32(K3, Qf[3], s);
            __builtin_amdgcn_s_setprio(0);
            if (anyzero) {
#pragma unroll
                for (int r = 0; r < 16; ++r) {
                    int kk = k0 + kt * 32 + (r & 3) + 8 * (r >> 2) + 4 * hf;
                    if (maskp[(size_t)n * S_ + kk] == 0) s[r] = -1e30f;
                }
            }
            float p[16];
#pragma unroll
            for (int r = 0; r < 16; ++r) p[r] = __builtin_amdgcn_exp2f(s[r]);
            lsum += ((((p[0] + p[1]) + (p[2] + p[3])) + ((p[4] + p[5]) + (p[6] + p[7])))
                  + (((p[8] + p[9]) + (p[10] + p[11])) + ((p[12] + p[13]) + (p[14] + p[15]))));
            u32 w0 = pack2(p[0],  p[1]),  w1 = pack2(p[2],  p[3]);
            u32 w2 = pack2(p[4],  p[5]),  w3 = pack2(p[6],  p[7]);
            u32 w4 = pack2(p[8],  p[9]),  w5 = pack2(p[10], p[11]);
            u32 w6 = pack2(p[12], p[13]), w7 = pack2(p[14], p[15]);
            swap32(w0, w2); swap32(w1, w3); swap32(w4, w6); swap32(w5, w7);
            u32x4 t0; t0[0] = w0; t0[1] = w1; t0[2] = w2; t0[3] = w3;
            u32x4 t1; t1[0] = w4; t1[1] = w5; t1[2] = w6; t1[3] = w7;
            bf16x8 P0 = __builtin_bit_cast(bf16x8, t0);
            bf16x8 P1 = __builtin_bit_cast(bf16x8, t1);
            bf16x8 V00 = *(const bf16x8*)(vbase + (0 * 32 + l31) * 128 + ((((kt * 2 + 0) * 2 + hf) * 16) ^ swz));
            bf16x8 V01 = *(const bf16x8*)(vbase + (0 * 32 + l31) * 128 + ((((kt * 2 + 1) * 2 + hf) * 16) ^ swz));
            bf16x8 V10 = *(const bf16x8*)(vbase + (1 * 32 + l31) * 128 + ((((kt * 2 + 0) * 2 + hf) * 16) ^ swz));
            bf16x8 V11 = *(const bf16x8*)(vbase + (1 * 32 + l31) * 128 + ((((kt * 2 + 1) * 2 + hf) * 16) ^ swz));
            __builtin_amdgcn_s_setprio(1);
            acc0 = mfma32(V00, P0, acc0); acc0 = mfma32(V01, P1, acc0);
            acc1 = mfma32(V10, P0, acc1); acc1 = mfma32(V11, P1, acc1);
            __builtin_amdgcn_s_setprio(0);
        }
        buf ^= 1;
    }

    lsum += __shfl_xor(lsum, 32);
    const float inv = 1.0f / lsum;
    const int qg = q0 + l31;
    __bf16* Ob = Xws + ((size_t)(n * S_ + qg)) * E_ + hd * 64;

    auto store_half = [&](const f32x16& a, int dv) {
#pragma unroll
        for (int rr = 0; rr < 4; ++rr) {
            bf16x4 o;
#pragma unroll
            for (int j = 0; j < 4; ++j) o[j] = (__bf16)(a[rr * 4 + j] * inv);
            *(bf16x4*)(Ob + dv * 32 + rr * 8 + hf * 4) = o;
        }
    };
    store_half(acc0, 0);
    store_half(acc1, 1);
}

// ------------------------------------------------------- output GEMM + bias
__global__ __launch_bounds__(256) void k_out(const __bf16* __restrict__ Xws,
                                             const __bf16* __restrict__ Wob,
                                             const float* __restrict__ bo,
                                             float* __restrict__ out) {
    const int lane = threadIdx.x & 63, wid = threadIdx.x >> 6;
    const int l31 = lane & 31, hf = lane >> 5, h8 = hf * 8;
    const int mb = blockIdx.x >> 4, ob = blockIdx.x & 15;
    const int m0 = mb * 128 + wid * 32, o0 = ob * 64;

    f32x16 acc0 = zero16(), acc1 = zero16();

    const __bf16* Xp = Xws + (size_t)(m0 + l31) * E_ + h8;
    const __bf16* W0 = Wob + (size_t)(o0 + l31) * E_ + h8;
    const __bf16* W1 = W0 + (size_t)32 * E_;

#pragma unroll 4
    for (int ks = 0; ks < 64; ++ks) {
        bf16x8 A = *(const bf16x8*)(Xp + ks * 16);
        acc0 = mfma32(A, *(const bf16x8*)(W0 + ks * 16), acc0);
        acc1 = mfma32(A, *(const bf16x8*)(W1 + ks * 16), acc1);
    }

    const float b0 = bo[o0 + l31], b1 = bo[o0 + 32 + l31];
#pragma unroll
    for (int rr = 0; rr < 4; ++rr)
#pragma unroll
        for (int j = 0; j < 4; ++j) {
            size_t m = (size_t)m0 + rr * 8 + hf * 4 + j;
            out[m * E_ + o0 + l31]      = acc0[rr * 4 + j] + b0;
            out[m * E_ + o0 + 32 + l31] = acc1[rr * 4 + j] + b1;
        }
}

extern "C" void kernel_launch(void* const* d_in, const int* in_sizes, int n_in,
                              void* d_out, int out_size, void* d_ws, size_t ws_size,
                              hipStream_t stream) {
    const float* vin  = (const float*)d_in[0];
    const float* kin  = (const float*)d_in[1];
    const float* qin  = (const float*)d_in[2];
    const int*   mask = (const int*)d_in[3];
    const float* Wv   = (const float*)d_in[4];
    const float* Wk   = (const float*)d_in[5];
    const float* Wq   = (const float*)d_in[6];
    const float* Wo   = (const float*)d_in[7];
    const float* bo   = (const float*)d_in[8];

    __bf16* Qws = (__bf16*)d_ws;                       // [64][2048][64]
    __bf16* Kws = Qws + (size_t)NH_ * S_ * 64;         // [64][2048][64] swizzled
    __bf16* Vt  = Kws + (size_t)NH_ * S_ * 64;         // [64][64][2048] swizzled
    __bf16* Xws = Vt  + (size_t)NH_ * S_ * 64;         // [4][2048][1024]
    __bf16* Wob = Xws + (size_t)4 * S_ * E_;           // [1024][1024]
    float* out = (float*)d_out;

    hipLaunchKernelGGL(k_cast_wo, dim3(512), dim3(256), 0, stream, Wo, Wob);
    hipLaunchKernelGGL(k_proj, dim3(2048, 1, 3), dim3(256), 0, stream,
                       vin, kin, qin, Wv, Wk, Wq, Qws, Kws, Vt);
    hipLaunchKernelGGL(k_attn, dim3(1024), dim3(256), 0, stream, Qws, Kws, Vt, mask, Xws);
    hipLaunchKernelGGL(k_out, dim3(1024), dim3(256), 0, stream, Xws, Wob, bo, out);
}

// Round 5
// 170.159 us; speedup vs baseline: 2.5642x; 1.3842x over previous
//
#include <hip/hip_runtime.h>
#include <hip/hip_bf16.h>

typedef __bf16 bf16x8 __attribute__((ext_vector_type(8)));
typedef __bf16 bf16x4 __attribute__((ext_vector_type(4)));
typedef __bf16 bf16x2 __attribute__((ext_vector_type(2)));
typedef float  f32x4  __attribute__((ext_vector_type(4)));
typedef float  f32x16 __attribute__((ext_vector_type(16)));
typedef unsigned int u32;
typedef u32 u32x4 __attribute__((ext_vector_type(4)));

#define S_  2048
#define E_  1024
#define NH_ 64

__device__ __forceinline__ f32x4 mfma16(bf16x8 a, bf16x8 b, f32x4 c) {
    return __builtin_amdgcn_mfma_f32_16x16x32_bf16(a, b, c, 0, 0, 0);
}
__device__ __forceinline__ f32x16 mfma32(bf16x8 a, bf16x8 b, f32x16 c) {
    return __builtin_amdgcn_mfma_f32_32x32x16_bf16(a, b, c, 0, 0, 0);
}
__device__ __forceinline__ u32 pack2(float a, float b) {
    bf16x2 t; t[0] = (__bf16)a; t[1] = (__bf16)b;
    return __builtin_bit_cast(u32, t);
}
__device__ __forceinline__ void swap32(u32& a, u32& b) {
    asm("v_permlane32_swap_b32 %0, %1" : "+v"(a), "+v"(b));
}
__device__ __forceinline__ f32x16 zero16() {
    f32x16 z;
#pragma unroll
    for (int i = 0; i < 16; ++i) z[i] = 0.f;
    return z;
}
__device__ __forceinline__ void gload_lds16(const void* g, void* l) {
    __builtin_amdgcn_global_load_lds(
        (const __attribute__((address_space(1))) unsigned int*)g,
        (__attribute__((address_space(3))) unsigned int*)l, 16, 0, 0);
}

// ------------------------------------------- Wo -> bf16 (pre-swizzled cols)
// element (o, e) stored at e ^ ((o&7)<<3) within its 64-col group, so k_out's
// linear global_load_lds + swizzled ds_read sees conflict-reduced layout.
__global__ __launch_bounds__(256) void k_cast_wo(const float* __restrict__ Wo,
                                                 __bf16* __restrict__ Wob) {
    int i = (blockIdx.x * 256 + threadIdx.x) * 8;
    int o = i >> 10, e0 = i & 1023;
    float4 a = *(const float4*)(Wo + i);
    float4 b = *(const float4*)(Wo + i + 4);
    bf16x8 f;
    f[0] = (__bf16)a.x; f[1] = (__bf16)a.y; f[2] = (__bf16)a.z; f[3] = (__bf16)a.w;
    f[4] = (__bf16)b.x; f[5] = (__bf16)b.y; f[6] = (__bf16)b.z; f[7] = (__bf16)b.w;
    int e_swz = (e0 & ~63) | ((e0 & 63) ^ ((o & 7) << 3));
    *(bf16x8*)(Wob + (size_t)o * 1024 + e_swz) = f;
}

// ------------------------------------------------- QKV per-head projections
// z=0: values -> Vt[nh][d][s^((d&7)<<3)]  (transposed via SWAPPED mfma operands)
// z=1: keys   -> Kws[nh][s][e^((s&7)<<3)] (XOR-swizzled cols)
// z=2: query  -> Qws[nh][s][e] plain, with log2(e)/32 folded into Wq.
__global__ __launch_bounds__(256) void k_proj(const float* __restrict__ vin,
                                              const float* __restrict__ kin,
                                              const float* __restrict__ qin,
                                              const float* __restrict__ Wv,
                                              const float* __restrict__ Wk,
                                              const float* __restrict__ Wq,
                                              __bf16* __restrict__ Qws,
                                              __bf16* __restrict__ Kws,
                                              __bf16* __restrict__ Vt) {
    const int z = blockIdx.z;
    const float* in = (z == 0) ? vin : ((z == 1) ? kin : qin);
    const float* W  = (z == 0) ? Wv  : ((z == 1) ? Wk  : Wq);
    const float scale = (z == 2) ? 0.04508422f : 1.0f;  // log2(e)/32
    const int bid  = blockIdx.x;
    const int nh   = bid >> 5;
    const int sblk = (bid & 31) << 6;
    const int n = nh >> 4, h = nh & 15;
    const int lane = threadIdx.x & 63, wid = threadIdx.x >> 6;
    const int l16 = lane & 15, g = lane >> 4;

    bf16x8 Bf[4][2];
#pragma unroll
    for (int nt = 0; nt < 4; ++nt)
#pragma unroll
        for (int ks = 0; ks < 2; ++ks) {
            const float* wp = W + (nt * 16 + l16) * 64 + ks * 32 + g * 8;
            float4 a = *(const float4*)wp;
            float4 b = *(const float4*)(wp + 4);
            bf16x8 f;
            f[0] = (__bf16)(a.x * scale); f[1] = (__bf16)(a.y * scale);
            f[2] = (__bf16)(a.z * scale); f[3] = (__bf16)(a.w * scale);
            f[4] = (__bf16)(b.x * scale); f[5] = (__bf16)(b.y * scale);
            f[6] = (__bf16)(b.z * scale); f[7] = (__bf16)(b.w * scale);
            Bf[nt][ks] = f;
        }

    const int s = sblk + wid * 16 + l16;
    const float* ip = in + ((size_t)n * S_ + s) * E_ + h * 64 + g * 8;
    bf16x8 Af[2];
#pragma unroll
    for (int ks = 0; ks < 2; ++ks) {
        float4 a = *(const float4*)(ip + ks * 32);
        float4 b = *(const float4*)(ip + ks * 32 + 4);
        bf16x8 f;
        f[0] = (__bf16)a.x; f[1] = (__bf16)a.y; f[2] = (__bf16)a.z; f[3] = (__bf16)a.w;
        f[4] = (__bf16)b.x; f[5] = (__bf16)b.y; f[6] = (__bf16)b.z; f[7] = (__bf16)b.w;
        Af[ks] = f;
    }

    f32x4 acc[4];
#pragma unroll
    for (int nt = 0; nt < 4; ++nt) { acc[nt][0] = 0.f; acc[nt][1] = 0.f; acc[nt][2] = 0.f; acc[nt][3] = 0.f; }

    if (z == 0) {
#pragma unroll
        for (int nt = 0; nt < 4; ++nt) {
            acc[nt] = mfma16(Bf[nt][0], Af[0], acc[nt]);
            acc[nt] = mfma16(Bf[nt][1], Af[1], acc[nt]);
        }
#pragma unroll
        for (int nt = 0; nt < 4; ++nt)
#pragma unroll
            for (int r = 0; r < 4; ++r) {
                int e = nt * 16 + g * 4 + r;
                int srow = sblk + wid * 16 + l16;
                int sc = srow ^ ((e & 7) << 3);   // V col swizzle (lane-contig within 32B)
                Vt[((size_t)nh * 64 + e) * S_ + sc] = (__bf16)acc[nt][r];
            }
    } else {
#pragma unroll
        for (int nt = 0; nt < 4; ++nt) {
            acc[nt] = mfma16(Af[0], Bf[nt][0], acc[nt]);
            acc[nt] = mfma16(Af[1], Bf[nt][1], acc[nt]);
        }
        if (z == 1) {
#pragma unroll
            for (int nt = 0; nt < 4; ++nt)
#pragma unroll
                for (int r = 0; r < 4; ++r) {
                    int srow = sblk + wid * 16 + g * 4 + r;
                    int ec = (nt * 16 + l16) ^ ((srow & 7) << 3);  // K col swizzle
                    Kws[((size_t)nh * S_ + srow) * 64 + ec] = (__bf16)acc[nt][r];
                }
        } else {
#pragma unroll
            for (int nt = 0; nt < 4; ++nt)
#pragma unroll
                for (int r = 0; r < 4; ++r) {
                    int srow = sblk + wid * 16 + g * 4 + r;
                    Qws[((size_t)nh * S_ + srow) * 64 + nt * 16 + l16] = (__bf16)acc[nt][r];
                }
        }
    }
}

// ----------------------------------------------------------- flash attention
// Block: 4 waves x 32 q = 128 q, one (n,h); grid 1024 = 4 blocks/CU.
// K/V tiles double-buffered via global_load_lds; softmax in-register.
// X output stored PRE-SWIZZLED within 64-col groups for k_out's LDS staging.
__global__ __launch_bounds__(256, 4) void k_attn(const __bf16* __restrict__ Qws,
                                                 const __bf16* __restrict__ Kws,
                                                 const __bf16* __restrict__ Vt,
                                                 const int* __restrict__ maskp,
                                                 __bf16* __restrict__ Xws) {
    __shared__ __align__(16) char lds[2][16384];  // [buf][K 8KB | V 8KB]
    const int tid = threadIdx.x, lane = tid & 63, wid = tid >> 6;
    const int l31 = lane & 31, hf = lane >> 5, h8 = hf * 8;
    const int v = blockIdx.x;
    const int u = v >> 3;
    const int nh = (v & 7) * 8 + (u & 7), qb = u >> 3;
    const int n = nh >> 4, hd = nh & 15;

    int az = 0;
    for (int i = tid; i < S_; i += 256) az |= (maskp[(size_t)n * S_ + i] == 0);
    const int anyzero = __syncthreads_or(az);

    const char* Kc = (const char*)(Kws + (size_t)nh * S_ * 64);
    const char* Vc = (const char*)(Vt  + (size_t)nh * 64 * S_);
    const __bf16* Qb = Qws + (size_t)nh * S_ * 64;

    const int q0 = qb * 128 + wid * 32;
    bf16x8 Qf[4];
#pragma unroll
    for (int dt = 0; dt < 4; ++dt)
        Qf[dt] = *(const bf16x8*)(Qb + (size_t)(q0 + l31) * 64 + dt * 16 + h8);

    f32x16 acc0 = zero16(), acc1 = zero16();
    float lsum = 0.f;

    auto stage = [&](int buf, int kb) {
        char* base = &lds[buf][0];
        const char* ks = Kc + (size_t)kb * 8192 + wid * 2048 + lane * 16;
        char* kd = base + wid * 2048;
        gload_lds16(ks, kd);
        gload_lds16(ks + 1024, kd + 1024);
        const int r0 = wid * 16 + (lane >> 3);
        const char* vs = Vc + (size_t)r0 * (S_ * 2) + (size_t)kb * 128 + (lane & 7) * 16;
        char* vd = base + 8192 + wid * 2048;
        gload_lds16(vs, vd);
        gload_lds16(vs + (size_t)8 * (S_ * 2), vd + 1024);
    };

    const int swz = (l31 & 7) << 4;

    stage(0, 0);
    int buf = 0;
    for (int kb = 0; kb < 32; ++kb) {
        __syncthreads();
        if (kb < 31) stage(buf ^ 1, kb + 1);
        char* base = &lds[buf][0];
        char* vbase = base + 8192;
        const int k0 = kb * 64;
#pragma unroll
        for (int kt = 0; kt < 2; ++kt) {
            bf16x8 K0 = *(const bf16x8*)(base + (kt * 32 + l31) * 128 + (((0 * 2 + hf) * 16) ^ swz));
            bf16x8 K1 = *(const bf16x8*)(base + (kt * 32 + l31) * 128 + (((1 * 2 + hf) * 16) ^ swz));
            bf16x8 K2 = *(const bf16x8*)(base + (kt * 32 + l31) * 128 + (((2 * 2 + hf) * 16) ^ swz));
            bf16x8 K3 = *(const bf16x8*)(base + (kt * 32 + l31) * 128 + (((3 * 2 + hf) * 16) ^ swz));
            __builtin_amdgcn_s_setprio(1);
            f32x16 s = zero16();
            s = mfma32(K0, Qf[0], s); s = mfma32(K1, Qf[1], s);
            s = mfma32(K2, Qf[2], s); s = mfma32(K3, Qf[3], s);
            __builtin_amdgcn_s_setprio(0);
            if (anyzero) {
#pragma unroll
                for (int r = 0; r < 16; ++r) {
                    int kk = k0 + kt * 32 + (r & 3) + 8 * (r >> 2) + 4 * hf;
                    if (maskp[(size_t)n * S_ + kk] == 0) s[r] = -1e30f;
                }
            }
            float p[16];
#pragma unroll
            for (int r = 0; r < 16; ++r) p[r] = __builtin_amdgcn_exp2f(s[r]);
            lsum += ((((p[0] + p[1]) + (p[2] + p[3])) + ((p[4] + p[5]) + (p[6] + p[7])))
                  + (((p[8] + p[9]) + (p[10] + p[11])) + ((p[12] + p[13]) + (p[14] + p[15]))));
            u32 w0 = pack2(p[0],  p[1]),  w1 = pack2(p[2],  p[3]);
            u32 w2 = pack2(p[4],  p[5]),  w3 = pack2(p[6],  p[7]);
            u32 w4 = pack2(p[8],  p[9]),  w5 = pack2(p[10], p[11]);
            u32 w6 = pack2(p[12], p[13]), w7 = pack2(p[14], p[15]);
            swap32(w0, w2); swap32(w1, w3); swap32(w4, w6); swap32(w5, w7);
            u32x4 t0; t0[0] = w0; t0[1] = w1; t0[2] = w2; t0[3] = w3;
            u32x4 t1; t1[0] = w4; t1[1] = w5; t1[2] = w6; t1[3] = w7;
            bf16x8 P0 = __builtin_bit_cast(bf16x8, t0);
            bf16x8 P1 = __builtin_bit_cast(bf16x8, t1);
            bf16x8 V00 = *(const bf16x8*)(vbase + (0 * 32 + l31) * 128 + ((((kt * 2 + 0) * 2 + hf) * 16) ^ swz));
            bf16x8 V01 = *(const bf16x8*)(vbase + (0 * 32 + l31) * 128 + ((((kt * 2 + 1) * 2 + hf) * 16) ^ swz));
            bf16x8 V10 = *(const bf16x8*)(vbase + (1 * 32 + l31) * 128 + ((((kt * 2 + 0) * 2 + hf) * 16) ^ swz));
            bf16x8 V11 = *(const bf16x8*)(vbase + (1 * 32 + l31) * 128 + ((((kt * 2 + 1) * 2 + hf) * 16) ^ swz));
            __builtin_amdgcn_s_setprio(1);
            acc0 = mfma32(V00, P0, acc0); acc0 = mfma32(V01, P1, acc0);
            acc1 = mfma32(V10, P0, acc1); acc1 = mfma32(V11, P1, acc1);
            __builtin_amdgcn_s_setprio(0);
        }
        buf ^= 1;
    }

    lsum += __shfl_xor(lsum, 32);
    const float inv = 1.0f / lsum;
    const int qg = q0 + l31;
    __bf16* Ob = Xws + ((size_t)(n * S_ + qg)) * E_ + hd * 64;
    const int qsw = (qg & 7) << 3;

    auto store_half = [&](const f32x16& a, int dv) {
#pragma unroll
        for (int rr = 0; rr < 4; ++rr) {
            bf16x4 o;
#pragma unroll
            for (int j = 0; j < 4; ++j) o[j] = (__bf16)(a[rr * 4 + j] * inv);
            int dsw = ((dv * 32 + rr * 8) ^ qsw) + hf * 4;  // pre-swizzle for k_out
            *(bf16x4*)(Ob + dsw) = o;
        }
    };
    store_half(acc0, 0);
    store_half(acc1, 1);
}

// ------------------------------------------------------- output GEMM + bias
// Y[m][o] = sum_e X[m][e]*Wo[o][e] + bo[o]; M=8192 N=1024 K=1024.
// 128x128 block tile, BK=64, LDS-staged (global_load_lds, double-buffered),
// swizzled ds_read_b128 (swizzle pre-applied in global X / Wob).
__global__ __launch_bounds__(256) void k_out(const __bf16* __restrict__ Xws,
                                             const __bf16* __restrict__ Wob,
                                             const float* __restrict__ bo,
                                             float* __restrict__ out) {
    __shared__ __align__(16) char Al[2][16384];
    __shared__ __align__(16) char Bl[2][16384];
    const int tid = threadIdx.x, lane = tid & 63, wid = tid >> 6;
    const int l31 = lane & 31, hf = lane >> 5;
    // XCD swizzle: 512 blocks = 64 mb x 8 ob; XCD x gets mb in [8x, 8x+8)
    const int v = blockIdx.x;
    const int id2 = (v & 7) * 64 + (v >> 3);
    const int mb = id2 >> 3, ob = id2 & 7;
    const int m0 = mb * 128, o0 = ob * 128;
    const int wr = wid >> 1, wc = wid & 1;

    const char* Xb = (const char*)Xws + (size_t)m0 * 2048;
    const char* Wb = (const char*)Wob + (size_t)o0 * 2048;
    const int r = tid >> 3, cb = (tid & 7) * 16;

    auto stage = [&](int buf, int kb) {
#pragma unroll
        for (int p = 0; p < 4; ++p) {
            gload_lds16(Xb + (size_t)(p * 32 + r) * 2048 + kb * 128 + cb,
                        &Al[buf][p * 4096 + wid * 1024]);
            gload_lds16(Wb + (size_t)(p * 32 + r) * 2048 + kb * 128 + cb,
                        &Bl[buf][p * 4096 + wid * 1024]);
        }
    };

    f32x16 acc00 = zero16(), acc01 = zero16(), acc10 = zero16(), acc11 = zero16();

    const int arow0 = (wr * 64 + l31) * 128;
    const int brow0 = (wc * 64 + l31) * 128;
    const int rsw = (l31 & 7) << 4;

    stage(0, 0);
    int buf = 0;
    for (int kb = 0; kb < 16; ++kb) {
        __syncthreads();
        if (kb < 15) stage(buf ^ 1, kb + 1);
        const char* ab = &Al[buf][0];
        const char* bb = &Bl[buf][0];
#pragma unroll
        for (int ks = 0; ks < 4; ++ks) {
            const int co = (ks * 32 + hf * 16) ^ rsw;
            bf16x8 A0 = *(const bf16x8*)(ab + arow0 + co);
            bf16x8 A1 = *(const bf16x8*)(ab + arow0 + 32 * 128 + co);
            bf16x8 B0 = *(const bf16x8*)(bb + brow0 + co);
            bf16x8 B1 = *(const bf16x8*)(bb + brow0 + 32 * 128 + co);
            __builtin_amdgcn_s_setprio(1);
            acc00 = mfma32(A0, B0, acc00);
            acc01 = mfma32(A0, B1, acc01);
            acc10 = mfma32(A1, B0, acc10);
            acc11 = mfma32(A1, B1, acc11);
            __builtin_amdgcn_s_setprio(0);
        }
        buf ^= 1;
    }

    const float bias0 = bo[o0 + wc * 64 + l31];
    const float bias1 = bo[o0 + wc * 64 + 32 + l31];
#pragma unroll
    for (int sm = 0; sm < 2; ++sm) {
        const f32x16& a0 = (sm == 0) ? acc00 : acc10;
        const f32x16& a1 = (sm == 0) ? acc01 : acc11;
#pragma unroll
        for (int rr = 0; rr < 4; ++rr)
#pragma unroll
            for (int j = 0; j < 4; ++j) {
                size_t m = (size_t)m0 + wr * 64 + sm * 32 + rr * 8 + hf * 4 + j;
                out[m * E_ + o0 + wc * 64 + l31]      = a0[rr * 4 + j] + bias0;
                out[m * E_ + o0 + wc * 64 + 32 + l31] = a1[rr * 4 + j] + bias1;
            }
    }
}

extern "C" void kernel_launch(void* const* d_in, const int* in_sizes, int n_in,
                              void* d_out, int out_size, void* d_ws, size_t ws_size,
                              hipStream_t stream) {
    const float* vin  = (const float*)d_in[0];
    const float* kin  = (const float*)d_in[1];
    const float* qin  = (const float*)d_in[2];
    const int*   mask = (const int*)d_in[3];
    const float* Wv   = (const float*)d_in[4];
    const float* Wk   = (const float*)d_in[5];
    const float* Wq   = (const float*)d_in[6];
    const float* Wo   = (const float*)d_in[7];
    const float* bo   = (const float*)d_in[8];

    __bf16* Qws = (__bf16*)d_ws;                       // [64][2048][64]
    __bf16* Kws = Qws + (size_t)NH_ * S_ * 64;         // [64][2048][64] swizzled
    __bf16* Vt  = Kws + (size_t)NH_ * S_ * 64;         // [64][64][2048] swizzled
    __bf16* Xws = Vt  + (size_t)NH_ * S_ * 64;         // [4][2048][1024] swizzled
    __bf16* Wob = Xws + (size_t)4 * S_ * E_;           // [1024][1024] swizzled
    float* out = (float*)d_out;

    hipLaunchKernelGGL(k_cast_wo, dim3(512), dim3(256), 0, stream, Wo, Wob);
    hipLaunchKernelGGL(k_proj, dim3(2048, 1, 3), dim3(256), 0, stream,
                       vin, kin, qin, Wv, Wk, Wq, Qws, Kws, Vt);
    hipLaunchKernelGGL(k_attn, dim3(1024), dim3(256), 0, stream, Qws, Kws, Vt, mask, Xws);
    hipLaunchKernelGGL(k_out, dim3(512), dim3(256), 0, stream, Xws, Wob, bo, out);
}

// Round 6
// 166.768 us; speedup vs baseline: 2.6163x; 1.0203x over previous
//
#include <hip/hip_runtime.h>
#include <hip/hip_bf16.h>

typedef __bf16 bf16x8 __attribute__((ext_vector_type(8)));
typedef __bf16 bf16x4 __attribute__((ext_vector_type(4)));
typedef __bf16 bf16x2 __attribute__((ext_vector_type(2)));
typedef float  f32x4  __attribute__((ext_vector_type(4)));
typedef float  f32x16 __attribute__((ext_vector_type(16)));
typedef unsigned int u32;
typedef u32 u32x4 __attribute__((ext_vector_type(4)));

#define S_  2048
#define E_  1024
#define NH_ 64

__device__ __forceinline__ f32x4 mfma16(bf16x8 a, bf16x8 b, f32x4 c) {
    return __builtin_amdgcn_mfma_f32_16x16x32_bf16(a, b, c, 0, 0, 0);
}
__device__ __forceinline__ f32x16 mfma32(bf16x8 a, bf16x8 b, f32x16 c) {
    return __builtin_amdgcn_mfma_f32_32x32x16_bf16(a, b, c, 0, 0, 0);
}
__device__ __forceinline__ u32 pack2(float a, float b) {
    bf16x2 t; t[0] = (__bf16)a; t[1] = (__bf16)b;
    return __builtin_bit_cast(u32, t);
}
__device__ __forceinline__ void swap32(u32& a, u32& b) {
    asm("v_permlane32_swap_b32 %0, %1" : "+v"(a), "+v"(b));
}
__device__ __forceinline__ f32x16 zero16() {
    f32x16 z;
#pragma unroll
    for (int i = 0; i < 16; ++i) z[i] = 0.f;
    return z;
}
__device__ __forceinline__ void gload_lds16(const void* g, void* l) {
    __builtin_amdgcn_global_load_lds(
        (const __attribute__((address_space(1))) unsigned int*)g,
        (__attribute__((address_space(3))) unsigned int*)l, 16, 0, 0);
}
// fragment = two ds_read_b64 at independently-swizzled 8B slots
__device__ __forceinline__ bf16x8 lds_frag(const char* p0, const char* p1) {
    bf16x4 lo = *(const bf16x4*)p0;
    bf16x4 hi = *(const bf16x4*)p1;
    bf16x8 f;
    f[0] = lo[0]; f[1] = lo[1]; f[2] = lo[2]; f[3] = lo[3];
    f[4] = hi[0]; f[5] = hi[1]; f[6] = hi[2]; f[7] = hi[3];
    return f;
}

// ------------------------------------------- Wo -> bf16 (pre-swizzled cols)
__global__ __launch_bounds__(256) void k_cast_wo(const float* __restrict__ Wo,
                                                 __bf16* __restrict__ Wob) {
    int i = (blockIdx.x * 256 + threadIdx.x) * 8;
    int o = i >> 10, e0 = i & 1023;
    float4 a = *(const float4*)(Wo + i);
    float4 b = *(const float4*)(Wo + i + 4);
    bf16x8 f;
    f[0] = (__bf16)a.x; f[1] = (__bf16)a.y; f[2] = (__bf16)a.z; f[3] = (__bf16)a.w;
    f[4] = (__bf16)b.x; f[5] = (__bf16)b.y; f[6] = (__bf16)b.z; f[7] = (__bf16)b.w;
    int e_swz = (e0 & ~63) | ((e0 & 63) ^ ((o & 7) << 3));
    *(bf16x8*)(Wob + (size_t)o * 1024 + e_swz) = f;
}

// ------------------------------------------------- QKV per-head projections
// z=0: values -> Vt[nh][d][s ^ (((d&7)<<3)|(((d>>3)&1)<<2))]  (transposed)
// z=1: keys   -> Kws[nh][s][e ^ (((s&7)<<3)|(((s>>3)&1)<<2))]
// z=2: query  -> Qws[nh][s][e] plain, with log2(e)/32 folded into Wq.
// 4-bit-row XOR (8B slots) makes k_attn's ds_read_b64 2-way = conflict-free.
__global__ __launch_bounds__(256) void k_proj(const float* __restrict__ vin,
                                              const float* __restrict__ kin,
                                              const float* __restrict__ qin,
                                              const float* __restrict__ Wv,
                                              const float* __restrict__ Wk,
                                              const float* __restrict__ Wq,
                                              __bf16* __restrict__ Qws,
                                              __bf16* __restrict__ Kws,
                                              __bf16* __restrict__ Vt) {
    const int z = blockIdx.z;
    const float* in = (z == 0) ? vin : ((z == 1) ? kin : qin);
    const float* W  = (z == 0) ? Wv  : ((z == 1) ? Wk  : Wq);
    const float scale = (z == 2) ? 0.04508422f : 1.0f;  // log2(e)/32
    const int bid  = blockIdx.x;
    const int nh   = bid >> 5;
    const int sblk = (bid & 31) << 6;
    const int n = nh >> 4, h = nh & 15;
    const int lane = threadIdx.x & 63, wid = threadIdx.x >> 6;
    const int l16 = lane & 15, g = lane >> 4;

    bf16x8 Bf[4][2];
#pragma unroll
    for (int nt = 0; nt < 4; ++nt)
#pragma unroll
        for (int ks = 0; ks < 2; ++ks) {
            const float* wp = W + (nt * 16 + l16) * 64 + ks * 32 + g * 8;
            float4 a = *(const float4*)wp;
            float4 b = *(const float4*)(wp + 4);
            bf16x8 f;
            f[0] = (__bf16)(a.x * scale); f[1] = (__bf16)(a.y * scale);
            f[2] = (__bf16)(a.z * scale); f[3] = (__bf16)(a.w * scale);
            f[4] = (__bf16)(b.x * scale); f[5] = (__bf16)(b.y * scale);
            f[6] = (__bf16)(b.z * scale); f[7] = (__bf16)(b.w * scale);
            Bf[nt][ks] = f;
        }

    const int s = sblk + wid * 16 + l16;
    const float* ip = in + ((size_t)n * S_ + s) * E_ + h * 64 + g * 8;
    bf16x8 Af[2];
#pragma unroll
    for (int ks = 0; ks < 2; ++ks) {
        float4 a = *(const float4*)(ip + ks * 32);
        float4 b = *(const float4*)(ip + ks * 32 + 4);
        bf16x8 f;
        f[0] = (__bf16)a.x; f[1] = (__bf16)a.y; f[2] = (__bf16)a.z; f[3] = (__bf16)a.w;
        f[4] = (__bf16)b.x; f[5] = (__bf16)b.y; f[6] = (__bf16)b.z; f[7] = (__bf16)b.w;
        Af[ks] = f;
    }

    f32x4 acc[4];
#pragma unroll
    for (int nt = 0; nt < 4; ++nt) { acc[nt][0] = 0.f; acc[nt][1] = 0.f; acc[nt][2] = 0.f; acc[nt][3] = 0.f; }

    if (z == 0) {
#pragma unroll
        for (int nt = 0; nt < 4; ++nt) {
            acc[nt] = mfma16(Bf[nt][0], Af[0], acc[nt]);
            acc[nt] = mfma16(Bf[nt][1], Af[1], acc[nt]);
        }
#pragma unroll
        for (int nt = 0; nt < 4; ++nt)
#pragma unroll
            for (int r = 0; r < 4; ++r) {
                int e = nt * 16 + g * 4 + r;
                int srow = sblk + wid * 16 + l16;
                int sc = srow ^ (((e & 7) << 3) | (((e >> 3) & 1) << 2));
                Vt[((size_t)nh * 64 + e) * S_ + sc] = (__bf16)acc[nt][r];
            }
    } else {
#pragma unroll
        for (int nt = 0; nt < 4; ++nt) {
            acc[nt] = mfma16(Af[0], Bf[nt][0], acc[nt]);
            acc[nt] = mfma16(Af[1], Bf[nt][1], acc[nt]);
        }
        if (z == 1) {
#pragma unroll
            for (int nt = 0; nt < 4; ++nt)
#pragma unroll
                for (int r = 0; r < 4; ++r) {
                    int srow = sblk + wid * 16 + g * 4 + r;
                    int ec = (nt * 16 + l16) ^ (((srow & 7) << 3) | (((srow >> 3) & 1) << 2));
                    Kws[((size_t)nh * S_ + srow) * 64 + ec] = (__bf16)acc[nt][r];
                }
        } else {
#pragma unroll
            for (int nt = 0; nt < 4; ++nt)
#pragma unroll
                for (int r = 0; r < 4; ++r) {
                    int srow = sblk + wid * 16 + g * 4 + r;
                    Qws[((size_t)nh * S_ + srow) * 64 + nt * 16 + l16] = (__bf16)acc[nt][r];
                }
        }
    }
}

// ----------------------------------------------------------- flash attention
// Block: 4 waves x 64 q = 256 q, one (n,h); grid 512 = 2 blocks/CU.
// K/V tiles (64k x 64d, 8KB+8KB) double-buffered via global_load_lds; one
// __syncthreads per tile. Fragments via ds_read_b64 pairs with 4-bit-row XOR
// swizzle (pre-applied in global) -> conflict-free. Softmax in-register.
__global__ __launch_bounds__(256, 2) void k_attn(const __bf16* __restrict__ Qws,
                                                 const __bf16* __restrict__ Kws,
                                                 const __bf16* __restrict__ Vt,
                                                 const int* __restrict__ maskp,
                                                 __bf16* __restrict__ Xws) {
    __shared__ __align__(16) char lds[2][16384];  // [buf][K 8KB | V 8KB]
    const int tid = threadIdx.x, lane = tid & 63, wid = tid >> 6;
    const int l31 = lane & 31, hf = lane >> 5, h8 = hf * 8;
    // XCD swizzle: 512 blocks = 8 xcd x (8 nh x 8 qb); XCD x gets nh [8x,8x+8)
    const int v = blockIdx.x;
    const int u = v >> 3;
    const int nh = (v & 7) * 8 + (u & 7), qb = u >> 3;
    const int n = nh >> 4, hd = nh & 15;

    int az = 0;
    for (int i = tid; i < S_; i += 256) az |= (maskp[(size_t)n * S_ + i] == 0);
    const int anyzero = __syncthreads_or(az);

    const char* Kc = (const char*)(Kws + (size_t)nh * S_ * 64);
    const char* Vc = (const char*)(Vt  + (size_t)nh * 64 * S_);
    const __bf16* Qb = Qws + (size_t)nh * S_ * 64;

    const int q0 = qb * 256 + wid * 64;
    bf16x8 QfA[4], QfB[4];
#pragma unroll
    for (int dt = 0; dt < 4; ++dt) {
        QfA[dt] = *(const bf16x8*)(Qb + (size_t)(q0 + l31) * 64 + dt * 16 + h8);
        QfB[dt] = *(const bf16x8*)(Qb + (size_t)(q0 + 32 + l31) * 64 + dt * 16 + h8);
    }

    f32x16 accA0 = zero16(), accA1 = zero16(), accB0 = zero16(), accB1 = zero16();
    float lsumA = 0.f, lsumB = 0.f;

    auto stage = [&](int buf, int kb) {
        char* base = &lds[buf][0];
        const char* ks = Kc + (size_t)kb * 8192 + wid * 2048 + lane * 16;
        char* kd = base + wid * 2048;
        gload_lds16(ks, kd);
        gload_lds16(ks + 1024, kd + 1024);
        const int r0 = wid * 16 + (lane >> 3);
        const char* vs = Vc + (size_t)r0 * (S_ * 2) + (size_t)kb * 128 + (lane & 7) * 16;
        char* vd = base + 8192 + wid * 2048;
        gload_lds16(vs, vd);
        gload_lds16(vs + (size_t)8 * (S_ * 2), vd + 1024);
    };

    // 4-bit row XOR, 8B slots: rows spread over 16 slots -> 2-way (free)
    const int fs = ((l31 & 7) << 4) | (((l31 >> 3) & 1) << 3);

    auto softmax = [&](const f32x16& s, float& ls, int kbase, bf16x8& P0, bf16x8& P1) {
        f32x16 sv = s;
        if (anyzero) {
#pragma unroll
            for (int r = 0; r < 16; ++r) {
                int kk = kbase + (r & 3) + 8 * (r >> 2) + 4 * hf;
                if (maskp[(size_t)n * S_ + kk] == 0) sv[r] = -1e30f;
            }
        }
        float p[16];
#pragma unroll
        for (int r = 0; r < 16; ++r) p[r] = __builtin_amdgcn_exp2f(sv[r]);
        ls += ((((p[0] + p[1]) + (p[2] + p[3])) + ((p[4] + p[5]) + (p[6] + p[7])))
            + (((p[8] + p[9]) + (p[10] + p[11])) + ((p[12] + p[13]) + (p[14] + p[15]))));
        u32 w0 = pack2(p[0],  p[1]),  w1 = pack2(p[2],  p[3]);
        u32 w2 = pack2(p[4],  p[5]),  w3 = pack2(p[6],  p[7]);
        u32 w4 = pack2(p[8],  p[9]),  w5 = pack2(p[10], p[11]);
        u32 w6 = pack2(p[12], p[13]), w7 = pack2(p[14], p[15]);
        swap32(w0, w2); swap32(w1, w3); swap32(w4, w6); swap32(w5, w7);
        u32x4 t0; t0[0] = w0; t0[1] = w1; t0[2] = w2; t0[3] = w3;
        u32x4 t1; t1[0] = w4; t1[1] = w5; t1[2] = w6; t1[3] = w7;
        P0 = __builtin_bit_cast(bf16x8, t0);
        P1 = __builtin_bit_cast(bf16x8, t1);
    };

    stage(0, 0);
    int buf = 0;
    for (int kb = 0; kb < 32; ++kb) {
        __syncthreads();
        if (kb < 31) stage(buf ^ 1, kb + 1);
        char* base = &lds[buf][0];
        char* vbase = base + 8192;
        const int k0 = kb * 64;
#pragma unroll
        for (int kt = 0; kt < 2; ++kt) {
            const char* krow = base + (kt * 32 + l31) * 128;
            bf16x8 K0 = lds_frag(krow + ((0 * 32 + hf * 16) ^ fs), krow + ((0 * 32 + hf * 16 + 8) ^ fs));
            bf16x8 K1 = lds_frag(krow + ((1 * 32 + hf * 16) ^ fs), krow + ((1 * 32 + hf * 16 + 8) ^ fs));
            bf16x8 K2 = lds_frag(krow + ((2 * 32 + hf * 16) ^ fs), krow + ((2 * 32 + hf * 16 + 8) ^ fs));
            bf16x8 K3 = lds_frag(krow + ((3 * 32 + hf * 16) ^ fs), krow + ((3 * 32 + hf * 16 + 8) ^ fs));
            __builtin_amdgcn_s_setprio(1);
            f32x16 sA = zero16(), sB = zero16();
            sA = mfma32(K0, QfA[0], sA); sA = mfma32(K1, QfA[1], sA);
            sA = mfma32(K2, QfA[2], sA); sA = mfma32(K3, QfA[3], sA);
            sB = mfma32(K0, QfB[0], sB); sB = mfma32(K1, QfB[1], sB);
            sB = mfma32(K2, QfB[2], sB); sB = mfma32(K3, QfB[3], sB);
            __builtin_amdgcn_s_setprio(0);
            // issue V reads before softmax so ds latency hides under VALU
            const char* v0row = vbase + (0 * 32 + l31) * 128;
            const char* v1row = vbase + (1 * 32 + l31) * 128;
            const int o0b = (kt * 2 + 0) * 32 + hf * 16;
            const int o1b = (kt * 2 + 1) * 32 + hf * 16;
            bf16x8 V00 = lds_frag(v0row + (o0b ^ fs), v0row + ((o0b + 8) ^ fs));
            bf16x8 V01 = lds_frag(v0row + (o1b ^ fs), v0row + ((o1b + 8) ^ fs));
            bf16x8 V10 = lds_frag(v1row + (o0b ^ fs), v1row + ((o0b + 8) ^ fs));
            bf16x8 V11 = lds_frag(v1row + (o1b ^ fs), v1row + ((o1b + 8) ^ fs));
            bf16x8 PA0, PA1, PB0, PB1;
            softmax(sA, lsumA, k0 + kt * 32, PA0, PA1);
            softmax(sB, lsumB, k0 + kt * 32, PB0, PB1);
            __builtin_amdgcn_s_setprio(1);
            accA0 = mfma32(V00, PA0, accA0); accA0 = mfma32(V01, PA1, accA0);
            accA1 = mfma32(V10, PA0, accA1); accA1 = mfma32(V11, PA1, accA1);
            accB0 = mfma32(V00, PB0, accB0); accB0 = mfma32(V01, PB1, accB0);
            accB1 = mfma32(V10, PB0, accB1); accB1 = mfma32(V11, PB1, accB1);
            __builtin_amdgcn_s_setprio(0);
        }
        buf ^= 1;
    }

    lsumA += __shfl_xor(lsumA, 32);
    lsumB += __shfl_xor(lsumB, 32);
    const float invA = 1.0f / lsumA, invB = 1.0f / lsumB;

    auto store_q = [&](const f32x16& a0, const f32x16& a1, int qg, float inv) {
        __bf16* Ob = Xws + ((size_t)(n * S_ + qg)) * E_ + hd * 64;
        const int qsw = (qg & 7) << 3;
#pragma unroll
        for (int dv = 0; dv < 2; ++dv) {
            const f32x16& a = dv ? a1 : a0;
#pragma unroll
            for (int rr = 0; rr < 4; ++rr) {
                bf16x4 o;
#pragma unroll
                for (int j = 0; j < 4; ++j) o[j] = (__bf16)(a[rr * 4 + j] * inv);
                int dsw = ((dv * 32 + rr * 8) ^ qsw) + hf * 4;  // pre-swizzle for k_out
                *(bf16x4*)(Ob + dsw) = o;
            }
        }
    };
    store_q(accA0, accA1, q0 + l31, invA);
    store_q(accB0, accB1, q0 + 32 + l31, invB);
}

// ------------------------------------------------------- output GEMM + bias
// 128x128 block tile, BK=64, LDS-staged (global_load_lds, double-buffered),
// swizzled ds_read_b128 (swizzle pre-applied in global X / Wob).
__global__ __launch_bounds__(256) void k_out(const __bf16* __restrict__ Xws,
                                             const __bf16* __restrict__ Wob,
                                             const float* __restrict__ bo,
                                             float* __restrict__ out) {
    __shared__ __align__(16) char Al[2][16384];
    __shared__ __align__(16) char Bl[2][16384];
    const int tid = threadIdx.x, lane = tid & 63, wid = tid >> 6;
    const int l31 = lane & 31, hf = lane >> 5;
    const int v = blockIdx.x;
    const int id2 = (v & 7) * 64 + (v >> 3);
    const int mb = id2 >> 3, ob = id2 & 7;
    const int m0 = mb * 128, o0 = ob * 128;
    const int wr = wid >> 1, wc = wid & 1;

    const char* Xb = (const char*)Xws + (size_t)m0 * 2048;
    const char* Wb = (const char*)Wob + (size_t)o0 * 2048;
    const int r = tid >> 3, cb = (tid & 7) * 16;

    auto stage = [&](int buf, int kb) {
#pragma unroll
        for (int p = 0; p < 4; ++p) {
            gload_lds16(Xb + (size_t)(p * 32 + r) * 2048 + kb * 128 + cb,
                        &Al[buf][p * 4096 + wid * 1024]);
            gload_lds16(Wb + (size_t)(p * 32 + r) * 2048 + kb * 128 + cb,
                        &Bl[buf][p * 4096 + wid * 1024]);
        }
    };

    f32x16 acc00 = zero16(), acc01 = zero16(), acc10 = zero16(), acc11 = zero16();

    const int arow0 = (wr * 64 + l31) * 128;
    const int brow0 = (wc * 64 + l31) * 128;
    const int rsw = (l31 & 7) << 4;

    stage(0, 0);
    int buf = 0;
    for (int kb = 0; kb < 16; ++kb) {
        __syncthreads();
        if (kb < 15) stage(buf ^ 1, kb + 1);
        const char* ab = &Al[buf][0];
        const char* bb = &Bl[buf][0];
#pragma unroll
        for (int ks = 0; ks < 4; ++ks) {
            const int co = (ks * 32 + hf * 16) ^ rsw;
            bf16x8 A0 = *(const bf16x8*)(ab + arow0 + co);
            bf16x8 A1 = *(const bf16x8*)(ab + arow0 + 32 * 128 + co);
            bf16x8 B0 = *(const bf16x8*)(bb + brow0 + co);
            bf16x8 B1 = *(const bf16x8*)(bb + brow0 + 32 * 128 + co);
            __builtin_amdgcn_s_setprio(1);
            acc00 = mfma32(A0, B0, acc00);
            acc01 = mfma32(A0, B1, acc01);
            acc10 = mfma32(A1, B0, acc10);
            acc11 = mfma32(A1, B1, acc11);
            __builtin_amdgcn_s_setprio(0);
        }
        buf ^= 1;
    }

    const float bias0 = bo[o0 + wc * 64 + l31];
    const float bias1 = bo[o0 + wc * 64 + 32 + l31];
#pragma unroll
    for (int sm = 0; sm < 2; ++sm) {
        const f32x16& a0 = (sm == 0) ? acc00 : acc10;
        const f32x16& a1 = (sm == 0) ? acc01 : acc11;
#pragma unroll
        for (int rr = 0; rr < 4; ++rr)
#pragma unroll
            for (int j = 0; j < 4; ++j) {
                size_t m = (size_t)m0 + wr * 64 + sm * 32 + rr * 8 + hf * 4 + j;
                out[m * E_ + o0 + wc * 64 + l31]      = a0[rr * 4 + j] + bias0;
                out[m * E_ + o0 + wc * 64 + 32 + l31] = a1[rr * 4 + j] + bias1;
            }
    }
}

extern "C" void kernel_launch(void* const* d_in, const int* in_sizes, int n_in,
                              void* d_out, int out_size, void* d_ws, size_t ws_size,
                              hipStream_t stream) {
    const float* vin  = (const float*)d_in[0];
    const float* kin  = (const float*)d_in[1];
    const float* qin  = (const float*)d_in[2];
    const int*   mask = (const int*)d_in[3];
    const float* Wv   = (const float*)d_in[4];
    const float* Wk   = (const float*)d_in[5];
    const float* Wq   = (const float*)d_in[6];
    const float* Wo   = (const float*)d_in[7];
    const float* bo   = (const float*)d_in[8];

    __bf16* Qws = (__bf16*)d_ws;                       // [64][2048][64]
    __bf16* Kws = Qws + (size_t)NH_ * S_ * 64;         // [64][2048][64] swizzled
    __bf16* Vt  = Kws + (size_t)NH_ * S_ * 64;         // [64][64][2048] swizzled
    __bf16* Xws = Vt  + (size_t)NH_ * S_ * 64;         // [4][2048][1024] swizzled
    __bf16* Wob = Xws + (size_t)4 * S_ * E_;           // [1024][1024] swizzled
    float* out = (float*)d_out;

    hipLaunchKernelGGL(k_cast_wo, dim3(512), dim3(256), 0, stream, Wo, Wob);
    hipLaunchKernelGGL(k_proj, dim3(2048, 1, 3), dim3(256), 0, stream,
                       vin, kin, qin, Wv, Wk, Wq, Qws, Kws, Vt);
    hipLaunchKernelGGL(k_attn, dim3(512), dim3(256), 0, stream, Qws, Kws, Vt, mask, Xws);
    hipLaunchKernelGGL(k_out, dim3(512), dim3(256), 0, stream, Xws, Wob, bo, out);
}